// Round 3
// baseline (137.230 us; speedup 1.0000x reference)
//
#include <hip/hip_runtime.h>
#include <hip/hip_bf16.h>
#include <math.h>
#include <stdint.h>

namespace {

constexpr int Bc = 16, Nc = 1024, Ec = 128, Hc = 8, KDc = 16, HKc = 128;
// 1/sqrt(KD) * log2(e): fold softmax scale + base-2 conversion into Q
constexpr float SCALE = 0.25f * 1.4426950408889634f;

typedef __attribute__((ext_vector_type(8))) short short8;
typedef __attribute__((ext_vector_type(16))) float f32x16;

__device__ inline uint16_t f2bf(float f) {
  __hip_bfloat16 h = __float2bfloat16(f);
  uint16_t s; __builtin_memcpy(&s, &h, 2);
  return s;
}

// ---------------- Kernel 1: fused QKV projection + adjacency bit-pack ----------------
// Fragment layouts identical to round 2 (verified end-to-end).
// Adjacency: wave gw packs 64-int chunks via ballot -> bits[row][32 words].
__global__ __launch_bounds__(256) void qkv_kernel(
    const float* __restrict__ hin,
    const float* __restrict__ Wq, const float* __restrict__ Wk, const float* __restrict__ Wv,
    const int* __restrict__ adj,
    uint16_t* __restrict__ Qf, uint16_t* __restrict__ Kf, uint16_t* __restrict__ Vf,
    uint32_t* __restrict__ bits)
{
  __shared__ float h_lds[16][Ec];
  const int t = threadIdx.x;
  const int row0 = blockIdx.x * 16;

  const float4* hsrc = reinterpret_cast<const float4*>(hin + (size_t)row0 * Ec);
  float4* hdst = reinterpret_cast<float4*>(&h_lds[0][0]);
  hdst[t] = hsrc[t]; hdst[t + 256] = hsrc[t + 256];

  // ---- adjacency bit-pack (overlaps with h staging latency / other waves' VALU) ----
  {
    const int gw = blockIdx.x * 4 + (t >> 6);   // global wave id, 4096 waves
    const int l = t & 63;
    const int* asrc = adj + (size_t)gw * 4096 + l;   // 64 chunks x 64 ints
    uint2* bdst = reinterpret_cast<uint2*>(bits) + (size_t)gw * 64;
    #pragma unroll 4
    for (int c = 0; c < 64; ++c) {
      const int v = asrc[(size_t)c * 64];
      const unsigned long long m = __ballot(v != 0);
      if (l == 0) bdst[c] = make_uint2((uint32_t)m, (uint32_t)(m >> 32));
    }
  }
  __syncthreads();

  const int c = t & 127, rg = t >> 7;
  const int head = c >> 4, kd = c & 15;
  const float* wq = Wq + head * (Ec * KDc) + kd;
  const float* wk = Wk + head * (Ec * KDc) + kd;
  const float* wv = Wv + head * (Ec * KDc) + kd;

  float aq[8], ak[8], av[8];
  #pragma unroll
  for (int r = 0; r < 8; ++r) { aq[r] = 0.f; ak[r] = 0.f; av[r] = 0.f; }

  #pragma unroll 4
  for (int e = 0; e < Ec; ++e) {
    const float q_ = wq[e * KDc];
    const float k_ = wk[e * KDc];
    const float v_ = wv[e * KDc];
    #pragma unroll
    for (int r = 0; r < 8; ++r) {
      const float hv = h_lds[rg * 8 + r][e];
      aq[r] = fmaf(hv, q_, aq[r]);
      ak[r] = fmaf(hv, k_, ak[r]);
      av[r] = fmaf(hv, v_, av[r]);
    }
  }

  const int b = row0 >> 10;
  const int h5 = (kd >> 2) & 1;
  const int elem = (kd & 3) + 4 * (kd >> 3);

  #pragma unroll
  for (int r = 0; r < 8; ++r) {
    const int n = (row0 & 1023) + rg * 8 + r;
    const int blk = n >> 5;
    const int lane = (n & 31) + 32 * h5;
    const size_t qkoff = ((((size_t)b * Hc + head) * 32 + blk) * 64 + lane) * 8 + elem;
    Qf[qkoff] = f2bf(aq[r] * SCALE);
    Kf[qkoff] = f2bf(ak[r]);
    const int half = (n >> 4) & 1, krow = n & 15;
    const int h5v = (krow >> 2) & 1;
    const int iv = (krow & 3) + 4 * (krow >> 3);
    const int lid = kd + 16 * h5v;
    const size_t voff = (((((size_t)b * Hc + head) * 32 + blk) * 2 + half) * 32 + lid) * 8 + iv;
    Vf[voff] = f2bf(av[r]);
  }
}

// ---------------- Kernel 2: MFMA masked flash attention + out-proj ----------------
// 1024 threads = 16 waves: wave = (head hd = w&7, key-half hs = w>>3).
// Each wave: 16 mblk iterations over its key half; fixed-M softmax (no max tracking);
// partials combined in LDS; fused output projection + residual.
__global__ __launch_bounds__(1024, 8) void attn_kernel(
    const uint16_t* __restrict__ Qf, const uint16_t* __restrict__ Kf,
    const uint16_t* __restrict__ Vf, const uint32_t* __restrict__ bits,
    const float* __restrict__ hin, const float* __restrict__ Wout,
    float* __restrict__ out)
{
  __shared__ uint32_t adj_lds[32][33];   // [q-row][word], padded
  __shared__ float heads[32][132];       // [q-row][h*16+kd], padded
  __shared__ float S_lds[8][32];         // [head][q-row]

  const int t = threadIdx.x;
  // XCD-aware swizzle: 512 blocks, 64 per XCD -> each XCD sees 2 batches' K/V
  const int bid = blockIdx.x;
  const int swz = (bid & 7) * 64 + (bid >> 3);
  const int b = swz >> 5;
  const int qblk = swz & 31;
  const int w = t >> 6, hd = w & 7, hs = w >> 3;
  const int l = t & 63, h5 = l >> 5, q = l & 31;

  // stage adjacency bit words: 32 rows x 32 words, fully coalesced
  adj_lds[t >> 5][t & 31] =
      bits[((size_t)b * Nc + qblk * 32 + (t >> 5)) * 32 + (t & 31)];

  const short8 qfrag = *reinterpret_cast<const short8*>(
      Qf + ((((size_t)b * Hc + hd) * 32 + qblk) * 64 + l) * 8);

  __syncthreads();

  f32x16 acc, zc;
  #pragma unroll
  for (int i = 0; i < 16; ++i) { acc[i] = 0.f; zc[i] = 0.f; }
  float S = 0.f;

  const uint16_t* kbase = Kf + (((size_t)b * Hc + hd) * 32 + hs * 16) * 512 + (size_t)l * 8;
  const uint16_t* vbase = Vf + (((size_t)b * Hc + hd) * 32 + hs * 16) * 512
                             + (size_t)(q + 16 * h5) * 8;

  #pragma unroll 2
  for (int mb = 0; mb < 16; ++mb) {
    const short8 kfrag = *reinterpret_cast<const short8*>(kbase + (size_t)mb * 512);
    f32x16 s = __builtin_amdgcn_mfma_f32_32x32x16_bf16(kfrag, qfrag, zc, 0, 0, 0);

    const uint32_t wsh = adj_lds[q][hs * 16 + mb] >> (4 * h5);
    float p[16];
    #pragma unroll
    for (int r = 0; r < 16; ++r) {
      const float e = __builtin_amdgcn_exp2f(s[r]);   // fixed-M: scores bounded ~2^25
      p[r] = (wsh & (1u << ((r & 3) + 8 * (r >> 2)))) ? e : 0.f;
    }
    S += (((p[0] + p[1]) + (p[2] + p[3])) + ((p[4] + p[5]) + (p[6] + p[7])))
       + (((p[8] + p[9]) + (p[10] + p[11])) + ((p[12] + p[13]) + (p[14] + p[15])));

    short8 pa0, pa1;
    #pragma unroll
    for (int i = 0; i < 8; ++i) { pa0[i] = (short)f2bf(p[i]); pa1[i] = (short)f2bf(p[i + 8]); }

    short8 v0, v1;
    if (q < 16) {
      const uint16_t* vp = vbase + (size_t)mb * 512;
      v0 = *reinterpret_cast<const short8*>(vp);
      v1 = *reinterpret_cast<const short8*>(vp + 256);
    } else {
      #pragma unroll
      for (int i = 0; i < 8; ++i) { v0[i] = 0; v1[i] = 0; }
    }
    acc = __builtin_amdgcn_mfma_f32_32x32x16_bf16(pa0, v0, acc, 0, 0, 0);
    acc = __builtin_amdgcn_mfma_f32_32x32x16_bf16(pa1, v1, acc, 0, 0, 0);
  }

  S += __shfl_xor(S, 32);

  // ---- combine key-halves through LDS (fixed M -> plain sums) ----
  if (hs == 0) {
    if (q < 16) {
      #pragma unroll
      for (int r = 0; r < 16; ++r)
        heads[(r & 3) + 8 * (r >> 2) + 4 * h5][hd * 16 + q] = acc[r];
    }
    if (l < 32) S_lds[hd][l] = S;
  }
  __syncthreads();
  if (hs == 1) {
    if (q < 16) {
      #pragma unroll
      for (int r = 0; r < 16; ++r)
        heads[(r & 3) + 8 * (r >> 2) + 4 * h5][hd * 16 + q] += acc[r];
    }
    if (l < 32) S_lds[hd][l] += S;
  }
  __syncthreads();
  if (t < 256) S_lds[t >> 5][t & 31] = 1.0f / S_lds[t >> 5][t & 31];
  __syncthreads();
  #pragma unroll
  for (int i = 0; i < 4; ++i) {
    const int idx = t + i * 1024;
    const int rr = idx >> 7, cc = idx & 127;
    heads[rr][cc] *= S_lds[cc >> 4][rr];
  }
  __syncthreads();

  // ---- output projection + residual: thread = (q2 = t>>5, eg = t&31 -> 4 e-cols) ----
  const int q2 = t >> 5, eg = t & 31;
  const size_t orow = (size_t)b * Nc + qblk * 32 + q2;
  float4 o = *(reinterpret_cast<const float4*>(hin + orow * Ec) + eg);
  #pragma unroll 4
  for (int hk = 0; hk < HKc; ++hk) {
    const float hv = heads[q2][hk];                       // 32-lane broadcast
    const float4 wv4 = *(reinterpret_cast<const float4*>(Wout + (size_t)hk * Ec) + eg);
    o.x = fmaf(hv, wv4.x, o.x); o.y = fmaf(hv, wv4.y, o.y);
    o.z = fmaf(hv, wv4.z, o.z); o.w = fmaf(hv, wv4.w, o.w);
  }
  *(reinterpret_cast<float4*>(out + orow * Ec) + eg) = o;
}

} // namespace

extern "C" void kernel_launch(void* const* d_in, const int* in_sizes, int n_in,
                              void* d_out, int out_size, void* d_ws, size_t ws_size,
                              hipStream_t stream) {
  (void)in_sizes; (void)n_in; (void)out_size; (void)ws_size;
  const float* h   = (const float*)d_in[0];
  const int*   adj = (const int*)d_in[1];
  const float* Wq  = (const float*)d_in[2];
  const float* Wk  = (const float*)d_in[3];
  const float* Wv  = (const float*)d_in[4];
  const float* Wo  = (const float*)d_in[5];
  float* out = (float*)d_out;

  // workspace: Qf/Kf/Vf bf16 fragment buffers (4 MB each) + adjacency bits (2 MB)
  uint16_t* Qf = (uint16_t*)d_ws;
  uint16_t* Kf = Qf + (size_t)Bc * Hc * Nc * KDc;
  uint16_t* Vf = Kf + (size_t)Bc * Hc * Nc * KDc;
  uint32_t* bits = (uint32_t*)(Vf + (size_t)Bc * Hc * Nc * KDc);

  qkv_kernel<<<Bc * Nc / 16, 256, 0, stream>>>(h, Wq, Wk, Wv, adj, Qf, Kf, Vf, bits);
  attn_kernel<<<Bc * (Nc / 32), 1024, 0, stream>>>(Qf, Kf, Vf, bits, h, Wo, out);
}

// Round 4
// 119.758 us; speedup vs baseline: 1.1459x; 1.1459x over previous
//
#include <hip/hip_runtime.h>
#include <hip/hip_bf16.h>
#include <math.h>
#include <stdint.h>

namespace {

constexpr int Bc = 16, Nc = 1024, Ec = 128, Hc = 8, KDc = 16, HKc = 128;
// 1/sqrt(KD) * log2(e): fold softmax scale + base-2 conversion into Q
constexpr float SCALE = 0.25f * 1.4426950408889634f;

typedef __attribute__((ext_vector_type(8))) short short8;
typedef __attribute__((ext_vector_type(16))) float f32x16;

__device__ inline uint16_t f2bf(float f) {
  __hip_bfloat16 h = __float2bfloat16(f);
  uint16_t s; __builtin_memcpy(&s, &h, 2);
  return s;
}

// ---------------- Kernel 1: fused QKV projection + adjacency bit-pack ----------------
// Fragment layouts identical to round 2/3 (verified end-to-end).
__global__ __launch_bounds__(256) void qkv_kernel(
    const float* __restrict__ hin,
    const float* __restrict__ Wq, const float* __restrict__ Wk, const float* __restrict__ Wv,
    const int* __restrict__ adj,
    uint16_t* __restrict__ Qf, uint16_t* __restrict__ Kf, uint16_t* __restrict__ Vf,
    uint32_t* __restrict__ bits)
{
  __shared__ float h_lds[16][Ec];
  const int t = threadIdx.x;
  const int row0 = blockIdx.x * 16;

  const float4* hsrc = reinterpret_cast<const float4*>(hin + (size_t)row0 * Ec);
  float4* hdst = reinterpret_cast<float4*>(&h_lds[0][0]);
  hdst[t] = hsrc[t]; hdst[t + 256] = hsrc[t + 256];

  // ---- adjacency bit-pack (overlaps with h staging / other waves' VALU) ----
  {
    const int gw = blockIdx.x * 4 + (t >> 6);   // global wave id, 4096 waves
    const int l = t & 63;
    const int* asrc = adj + (size_t)gw * 4096 + l;   // 64 chunks x 64 ints
    uint2* bdst = reinterpret_cast<uint2*>(bits) + (size_t)gw * 64;
    #pragma unroll 4
    for (int c = 0; c < 64; ++c) {
      const int v = asrc[(size_t)c * 64];
      const unsigned long long m = __ballot(v != 0);
      if (l == 0) bdst[c] = make_uint2((uint32_t)m, (uint32_t)(m >> 32));
    }
  }
  __syncthreads();

  const int c = t & 127, rg = t >> 7;
  const int head = c >> 4, kd = c & 15;
  const float* wq = Wq + head * (Ec * KDc) + kd;
  const float* wk = Wk + head * (Ec * KDc) + kd;
  const float* wv = Wv + head * (Ec * KDc) + kd;

  float aq[8], ak[8], av[8];
  #pragma unroll
  for (int r = 0; r < 8; ++r) { aq[r] = 0.f; ak[r] = 0.f; av[r] = 0.f; }

  // float4 LDS reads (ds_read_b128): 4x fewer LDS ops than scalar
  #pragma unroll 2
  for (int e4 = 0; e4 < Ec / 4; ++e4) {
    const int e0 = e4 * 4;
    float4 hv4[8];
    #pragma unroll
    for (int r = 0; r < 8; ++r)
      hv4[r] = *reinterpret_cast<const float4*>(&h_lds[rg * 8 + r][e0]);
    #pragma unroll
    for (int j = 0; j < 4; ++j) {
      const float q_ = wq[(e0 + j) * KDc];
      const float k_ = wk[(e0 + j) * KDc];
      const float v_ = wv[(e0 + j) * KDc];
      #pragma unroll
      for (int r = 0; r < 8; ++r) {
        const float hv = (&hv4[r].x)[j];   // static index (fully unrolled)
        aq[r] = fmaf(hv, q_, aq[r]);
        ak[r] = fmaf(hv, k_, ak[r]);
        av[r] = fmaf(hv, v_, av[r]);
      }
    }
  }

  const int b = row0 >> 10;
  const int h5 = (kd >> 2) & 1;
  const int elem = (kd & 3) + 4 * (kd >> 3);

  #pragma unroll
  for (int r = 0; r < 8; ++r) {
    const int n = (row0 & 1023) + rg * 8 + r;
    const int blk = n >> 5;
    const int lane = (n & 31) + 32 * h5;
    const size_t qkoff = ((((size_t)b * Hc + head) * 32 + blk) * 64 + lane) * 8 + elem;
    Qf[qkoff] = f2bf(aq[r] * SCALE);
    Kf[qkoff] = f2bf(ak[r]);
    const int half = (n >> 4) & 1, krow = n & 15;
    const int h5v = (krow >> 2) & 1;
    const int iv = (krow & 3) + 4 * (krow >> 3);
    const int lid = kd + 16 * h5v;
    const size_t voff = (((((size_t)b * Hc + head) * 32 + blk) * 2 + half) * 32 + lid) * 8 + iv;
    Vf[voff] = f2bf(av[r]);
  }
}

// ---------------- Kernel 2: MFMA masked flash attention + out-proj ----------------
// 1024 threads = 16 waves: wave = (head hd = w&7, key-half hs = w>>3).
// Fixed-M softmax (scores bounded); S computed by MFMA via a ones-column in V
// (B cols 16..31 were unused zero-padding; col 16 = ones -> acc col16 = sum p).
__global__ __launch_bounds__(1024, 4) void attn_kernel(
    const uint16_t* __restrict__ Qf, const uint16_t* __restrict__ Kf,
    const uint16_t* __restrict__ Vf, const uint32_t* __restrict__ bits,
    const float* __restrict__ hin, const float* __restrict__ Wout,
    float* __restrict__ out)
{
  __shared__ uint32_t adj_lds[32][33];   // [q-row][word], padded
  __shared__ float heads[32][132];       // [q-row][h*16+kd], padded
  __shared__ float S_lds[8][32];         // [head][q-row]

  const int t = threadIdx.x;
  // XCD-aware swizzle: 512 blocks, 64 per XCD -> each XCD sees 2 batches' K/V
  const int bid = blockIdx.x;
  const int swz = (bid & 7) * 64 + (bid >> 3);
  const int b = swz >> 5;
  const int qblk = swz & 31;
  const int w = t >> 6, hd = w & 7, hs = w >> 3;
  const int l = t & 63, h5 = l >> 5, q = l & 31;

  // stage adjacency bit words: 32 rows x 32 words, fully coalesced
  adj_lds[t >> 5][t & 31] =
      bits[((size_t)b * Nc + qblk * 32 + (t >> 5)) * 32 + (t & 31)];

  const short8 qfrag = *reinterpret_cast<const short8*>(
      Qf + ((((size_t)b * Hc + hd) * 32 + qblk) * 64 + l) * 8);

  __syncthreads();

  f32x16 acc, zc;
  #pragma unroll
  for (int i = 0; i < 16; ++i) { acc[i] = 0.f; zc[i] = 0.f; }

  const uint16_t* kbase = Kf + (((size_t)b * Hc + hd) * 32 + hs * 16) * 512 + (size_t)l * 8;
  const uint16_t* vbase = Vf + (((size_t)b * Hc + hd) * 32 + hs * 16) * 512
                             + (size_t)(q + 16 * h5) * 8;

  // V B-operand per lane: q<16 -> V data; q==16 -> ones (S column); else zeros
  short8 vzero;
  #pragma unroll
  for (int i = 0; i < 8; ++i) vzero[i] = (q == 16) ? (short)0x3F80 : (short)0;

  #pragma unroll 2
  for (int mb = 0; mb < 16; ++mb) {
    const short8 kfrag = *reinterpret_cast<const short8*>(kbase + (size_t)mb * 512);
    f32x16 s = __builtin_amdgcn_mfma_f32_32x32x16_bf16(kfrag, qfrag, zc, 0, 0, 0);

    const uint32_t wsh = adj_lds[q][hs * 16 + mb] >> (4 * h5);
    float p[16];
    #pragma unroll
    for (int r = 0; r < 16; ++r) {
      const float e = __builtin_amdgcn_exp2f(s[r]);   // fixed-M: scores bounded
      const uint32_t lm = (uint32_t)__builtin_amdgcn_sbfe(
          (int)wsh, (r & 3) + 8 * (r >> 2), 1);        // 0 or 0xFFFFFFFF
      p[r] = __uint_as_float(__float_as_uint(e) & lm);
    }

    short8 pa0, pa1;
    #pragma unroll
    for (int i = 0; i < 8; ++i) { pa0[i] = (short)f2bf(p[i]); pa1[i] = (short)f2bf(p[i + 8]); }

    short8 v0 = vzero, v1 = vzero;
    if (q < 16) {
      const uint16_t* vp = vbase + (size_t)mb * 512;
      v0 = *reinterpret_cast<const short8*>(vp);
      v1 = *reinterpret_cast<const short8*>(vp + 256);
    }
    acc = __builtin_amdgcn_mfma_f32_32x32x16_bf16(pa0, v0, acc, 0, 0, 0);
    acc = __builtin_amdgcn_mfma_f32_32x32x16_bf16(pa1, v1, acc, 0, 0, 0);
  }

  // ---- combine key-halves through LDS; S sits in acc of q==16 lanes ----
  if (hs == 0) {
    if (q < 16) {
      #pragma unroll
      for (int r = 0; r < 16; ++r)
        heads[(r & 3) + 8 * (r >> 2) + 4 * h5][hd * 16 + q] = acc[r];
    } else if (q == 16) {
      #pragma unroll
      for (int r = 0; r < 16; ++r)
        S_lds[hd][(r & 3) + 8 * (r >> 2) + 4 * h5] = acc[r];
    }
  }
  __syncthreads();
  if (hs == 1) {
    if (q < 16) {
      #pragma unroll
      for (int r = 0; r < 16; ++r)
        heads[(r & 3) + 8 * (r >> 2) + 4 * h5][hd * 16 + q] += acc[r];
    } else if (q == 16) {
      #pragma unroll
      for (int r = 0; r < 16; ++r)
        S_lds[hd][(r & 3) + 8 * (r >> 2) + 4 * h5] += acc[r];
    }
  }
  __syncthreads();
  if (t < 256) S_lds[t >> 5][t & 31] = 1.0f / S_lds[t >> 5][t & 31];
  __syncthreads();
  #pragma unroll
  for (int i = 0; i < 4; ++i) {
    const int idx = t + i * 1024;
    const int rr = idx >> 7, cc = idx & 127;
    heads[rr][cc] *= S_lds[cc >> 4][rr];
  }
  __syncthreads();

  // ---- output projection + residual: thread = (q2 = t>>5, eg = t&31 -> 4 e-cols) ----
  const int q2 = t >> 5, eg = t & 31;
  const size_t orow = (size_t)b * Nc + qblk * 32 + q2;
  float4 o = *(reinterpret_cast<const float4*>(hin + orow * Ec) + eg);
  #pragma unroll 4
  for (int hk = 0; hk < HKc; ++hk) {
    const float hv = heads[q2][hk];                       // 32-lane broadcast
    const float4 wv4 = *(reinterpret_cast<const float4*>(Wout + (size_t)hk * Ec) + eg);
    o.x = fmaf(hv, wv4.x, o.x); o.y = fmaf(hv, wv4.y, o.y);
    o.z = fmaf(hv, wv4.z, o.z); o.w = fmaf(hv, wv4.w, o.w);
  }
  *(reinterpret_cast<float4*>(out + orow * Ec) + eg) = o;
}

} // namespace

extern "C" void kernel_launch(void* const* d_in, const int* in_sizes, int n_in,
                              void* d_out, int out_size, void* d_ws, size_t ws_size,
                              hipStream_t stream) {
  (void)in_sizes; (void)n_in; (void)out_size; (void)ws_size;
  const float* h   = (const float*)d_in[0];
  const int*   adj = (const int*)d_in[1];
  const float* Wq  = (const float*)d_in[2];
  const float* Wk  = (const float*)d_in[3];
  const float* Wv  = (const float*)d_in[4];
  const float* Wo  = (const float*)d_in[5];
  float* out = (float*)d_out;

  // workspace: Qf/Kf/Vf bf16 fragment buffers (4 MB each) + adjacency bits (2 MB)
  uint16_t* Qf = (uint16_t*)d_ws;
  uint16_t* Kf = Qf + (size_t)Bc * Hc * Nc * KDc;
  uint16_t* Vf = Kf + (size_t)Bc * Hc * Nc * KDc;
  uint32_t* bits = (uint32_t*)(Vf + (size_t)Bc * Hc * Nc * KDc);

  qkv_kernel<<<Bc * Nc / 16, 256, 0, stream>>>(h, Wq, Wk, Wv, adj, Qf, Kf, Vf, bits);
  attn_kernel<<<Bc * (Nc / 32), 1024, 0, stream>>>(Qf, Kf, Vf, bits, h, Wo, out);
}

// Round 6
// 116.998 us; speedup vs baseline: 1.1729x; 1.0236x over previous
//
#include <hip/hip_runtime.h>
#include <hip/hip_bf16.h>
#include <math.h>
#include <stdint.h>

namespace {

constexpr int Bc = 16, Nc = 1024, Ec = 128, Hc = 8, KDc = 16, HKc = 128;
// 1/sqrt(KD) * log2(e): fold softmax scale + base-2 conversion into Q
constexpr float SCALE = 0.25f * 1.4426950408889634f;

typedef __attribute__((ext_vector_type(8))) short short8;
typedef __attribute__((ext_vector_type(16))) float f32x16;

__device__ inline uint16_t f2bf(float f) {
  __hip_bfloat16 h = __float2bfloat16(f);
  uint16_t s; __builtin_memcpy(&s, &h, 2);
  return s;
}

// ---------------- Kernel 1: fused QKV projection + adjacency bit-pack ----------------
// (round-3 structure, post-timing validated; pack loop unroll 4 -> 8)
__global__ __launch_bounds__(256) void qkv_kernel(
    const float* __restrict__ hin,
    const float* __restrict__ Wq, const float* __restrict__ Wk, const float* __restrict__ Wv,
    const int* __restrict__ adj,
    uint16_t* __restrict__ Qf, uint16_t* __restrict__ Kf, uint16_t* __restrict__ Vf,
    uint32_t* __restrict__ bits)
{
  __shared__ float h_lds[16][Ec];
  const int t = threadIdx.x;
  const int row0 = blockIdx.x * 16;

  const float4* hsrc = reinterpret_cast<const float4*>(hin + (size_t)row0 * Ec);
  float4* hdst = reinterpret_cast<float4*>(&h_lds[0][0]);
  hdst[t] = hsrc[t]; hdst[t + 256] = hsrc[t + 256];

  // ---- adjacency bit-pack (overlaps with h staging / other waves' VALU) ----
  {
    const int gw = blockIdx.x * 4 + (t >> 6);   // global wave id, 4096 waves
    const int l = t & 63;
    const int* asrc = adj + (size_t)gw * 4096 + l;   // 64 chunks x 64 ints
    uint2* bdst = reinterpret_cast<uint2*>(bits) + (size_t)gw * 64;
    #pragma unroll 8
    for (int c = 0; c < 64; ++c) {
      const int v = asrc[(size_t)c * 64];
      const unsigned long long m = __ballot(v != 0);
      if (l == 0) bdst[c] = make_uint2((uint32_t)m, (uint32_t)(m >> 32));
    }
  }
  __syncthreads();

  const int c = t & 127, rg = t >> 7;
  const int head = c >> 4, kd = c & 15;
  const float* wq = Wq + head * (Ec * KDc) + kd;
  const float* wk = Wk + head * (Ec * KDc) + kd;
  const float* wv = Wv + head * (Ec * KDc) + kd;

  float aq[8], ak[8], av[8];
  #pragma unroll
  for (int r = 0; r < 8; ++r) { aq[r] = 0.f; ak[r] = 0.f; av[r] = 0.f; }

  #pragma unroll 4
  for (int e = 0; e < Ec; ++e) {
    const float q_ = wq[e * KDc];
    const float k_ = wk[e * KDc];
    const float v_ = wv[e * KDc];
    #pragma unroll
    for (int r = 0; r < 8; ++r) {
      const float hv = h_lds[rg * 8 + r][e];   // LDS broadcast within wave
      aq[r] = fmaf(hv, q_, aq[r]);
      ak[r] = fmaf(hv, k_, ak[r]);
      av[r] = fmaf(hv, v_, av[r]);
    }
  }

  const int b = row0 >> 10;
  const int h5 = (kd >> 2) & 1;
  const int elem = (kd & 3) + 4 * (kd >> 3);

  #pragma unroll
  for (int r = 0; r < 8; ++r) {
    const int n = (row0 & 1023) + rg * 8 + r;
    const int blk = n >> 5;
    const int lane = (n & 31) + 32 * h5;
    const size_t qkoff = ((((size_t)b * Hc + head) * 32 + blk) * 64 + lane) * 8 + elem;
    Qf[qkoff] = f2bf(aq[r] * SCALE);
    Kf[qkoff] = f2bf(ak[r]);
    const int half = (n >> 4) & 1, krow = n & 15;
    const int h5v = (krow >> 2) & 1;
    const int iv = (krow & 3) + 4 * (krow >> 3);
    const int lid = kd + 16 * h5v;
    const size_t voff = (((((size_t)b * Hc + head) * 32 + blk) * 2 + half) * 32 + lid) * 8 + iv;
    Vf[voff] = f2bf(av[r]);
  }
}

// ---------------- Kernel 2: MFMA masked flash attention + out-proj ----------------
// (byte-identical to round 4 — post-timing validated, 104 -> ~40 us)
__global__ __launch_bounds__(1024, 4) void attn_kernel(
    const uint16_t* __restrict__ Qf, const uint16_t* __restrict__ Kf,
    const uint16_t* __restrict__ Vf, const uint32_t* __restrict__ bits,
    const float* __restrict__ hin, const float* __restrict__ Wout,
    float* __restrict__ out)
{
  __shared__ uint32_t adj_lds[32][33];   // [q-row][word], padded
  __shared__ float heads[32][132];       // [q-row][h*16+kd], padded
  __shared__ float S_lds[8][32];         // [head][q-row]

  const int t = threadIdx.x;
  // XCD-aware swizzle: 512 blocks, 64 per XCD -> each XCD sees 2 batches' K/V
  const int bid = blockIdx.x;
  const int swz = (bid & 7) * 64 + (bid >> 3);
  const int b = swz >> 5;
  const int qblk = swz & 31;
  const int w = t >> 6, hd = w & 7, hs = w >> 3;
  const int l = t & 63, h5 = l >> 5, q = l & 31;

  // stage adjacency bit words: 32 rows x 32 words, fully coalesced
  adj_lds[t >> 5][t & 31] =
      bits[((size_t)b * Nc + qblk * 32 + (t >> 5)) * 32 + (t & 31)];

  const short8 qfrag = *reinterpret_cast<const short8*>(
      Qf + ((((size_t)b * Hc + hd) * 32 + qblk) * 64 + l) * 8);

  __syncthreads();

  f32x16 acc, zc;
  #pragma unroll
  for (int i = 0; i < 16; ++i) { acc[i] = 0.f; zc[i] = 0.f; }

  const uint16_t* kbase = Kf + (((size_t)b * Hc + hd) * 32 + hs * 16) * 512 + (size_t)l * 8;
  const uint16_t* vbase = Vf + (((size_t)b * Hc + hd) * 32 + hs * 16) * 512
                             + (size_t)(q + 16 * h5) * 8;

  // V B-operand per lane: q<16 -> V data; q==16 -> ones (S column); else zeros
  short8 vzero;
  #pragma unroll
  for (int i = 0; i < 8; ++i) vzero[i] = (q == 16) ? (short)0x3F80 : (short)0;

  #pragma unroll 2
  for (int mb = 0; mb < 16; ++mb) {
    const short8 kfrag = *reinterpret_cast<const short8*>(kbase + (size_t)mb * 512);
    f32x16 s = __builtin_amdgcn_mfma_f32_32x32x16_bf16(kfrag, qfrag, zc, 0, 0, 0);

    const uint32_t wsh = adj_lds[q][hs * 16 + mb] >> (4 * h5);
    float p[16];
    #pragma unroll
    for (int r = 0; r < 16; ++r) {
      const float e = __builtin_amdgcn_exp2f(s[r]);   // fixed-M: scores bounded
      const uint32_t lm = (uint32_t)__builtin_amdgcn_sbfe(
          (int)wsh, (r & 3) + 8 * (r >> 2), 1);        // 0 or 0xFFFFFFFF
      p[r] = __uint_as_float(__float_as_uint(e) & lm);
    }

    short8 pa0, pa1;
    #pragma unroll
    for (int i = 0; i < 8; ++i) { pa0[i] = (short)f2bf(p[i]); pa1[i] = (short)f2bf(p[i + 8]); }

    short8 v0 = vzero, v1 = vzero;
    if (q < 16) {
      const uint16_t* vp = vbase + (size_t)mb * 512;
      v0 = *reinterpret_cast<const short8*>(vp);
      v1 = *reinterpret_cast<const short8*>(vp + 256);
    }
    acc = __builtin_amdgcn_mfma_f32_32x32x16_bf16(pa0, v0, acc, 0, 0, 0);
    acc = __builtin_amdgcn_mfma_f32_32x32x16_bf16(pa1, v1, acc, 0, 0, 0);
  }

  // ---- combine key-halves through LDS; S sits in acc of q==16 lanes ----
  if (hs == 0) {
    if (q < 16) {
      #pragma unroll
      for (int r = 0; r < 16; ++r)
        heads[(r & 3) + 8 * (r >> 2) + 4 * h5][hd * 16 + q] = acc[r];
    } else if (q == 16) {
      #pragma unroll
      for (int r = 0; r < 16; ++r)
        S_lds[hd][(r & 3) + 8 * (r >> 2) + 4 * h5] = acc[r];
    }
  }
  __syncthreads();
  if (hs == 1) {
    if (q < 16) {
      #pragma unroll
      for (int r = 0; r < 16; ++r)
        heads[(r & 3) + 8 * (r >> 2) + 4 * h5][hd * 16 + q] += acc[r];
    } else if (q == 16) {
      #pragma unroll
      for (int r = 0; r < 16; ++r)
        S_lds[hd][(r & 3) + 8 * (r >> 2) + 4 * h5] += acc[r];
    }
  }
  __syncthreads();
  if (t < 256) S_lds[t >> 5][t & 31] = 1.0f / S_lds[t >> 5][t & 31];
  __syncthreads();
  #pragma unroll
  for (int i = 0; i < 4; ++i) {
    const int idx = t + i * 1024;
    const int rr = idx >> 7, cc = idx & 127;
    heads[rr][cc] *= S_lds[cc >> 4][rr];
  }
  __syncthreads();

  // ---- output projection + residual: thread = (q2 = t>>5, eg = t&31 -> 4 e-cols) ----
  const int q2 = t >> 5, eg = t & 31;
  const size_t orow = (size_t)b * Nc + qblk * 32 + q2;
  float4 o = *(reinterpret_cast<const float4*>(hin + orow * Ec) + eg);
  #pragma unroll 4
  for (int hk = 0; hk < HKc; ++hk) {
    const float hv = heads[q2][hk];                       // 32-lane broadcast
    const float4 wv4 = *(reinterpret_cast<const float4*>(Wout + (size_t)hk * Ec) + eg);
    o.x = fmaf(hv, wv4.x, o.x); o.y = fmaf(hv, wv4.y, o.y);
    o.z = fmaf(hv, wv4.z, o.z); o.w = fmaf(hv, wv4.w, o.w);
  }
  *(reinterpret_cast<float4*>(out + orow * Ec) + eg) = o;
}

} // namespace

extern "C" void kernel_launch(void* const* d_in, const int* in_sizes, int n_in,
                              void* d_out, int out_size, void* d_ws, size_t ws_size,
                              hipStream_t stream) {
  (void)in_sizes; (void)n_in; (void)out_size; (void)ws_size;
  const float* h   = (const float*)d_in[0];
  const int*   adj = (const int*)d_in[1];
  const float* Wq  = (const float*)d_in[2];
  const float* Wk  = (const float*)d_in[3];
  const float* Wv  = (const float*)d_in[4];
  const float* Wo  = (const float*)d_in[5];
  float* out = (float*)d_out;

  // workspace: Qf/Kf/Vf bf16 fragment buffers (4 MB each) + adjacency bits (2 MB)
  uint16_t* Qf = (uint16_t*)d_ws;
  uint16_t* Kf = Qf + (size_t)Bc * Hc * Nc * KDc;
  uint16_t* Vf = Kf + (size_t)Bc * Hc * Nc * KDc;
  uint32_t* bits = (uint32_t*)(Vf + (size_t)Bc * Hc * Nc * KDc);

  qkv_kernel<<<Bc * Nc / 16, 256, 0, stream>>>(h, Wq, Wk, Wv, adj, Qf, Kf, Vf, bits);
  attn_kernel<<<Bc * (Nc / 32), 1024, 0, stream>>>(Qf, Kf, Vf, bits, h, Wo, out);
}

// Round 7
// 113.588 us; speedup vs baseline: 1.2081x; 1.0300x over previous
//
#include <hip/hip_runtime.h>
#include <hip/hip_bf16.h>
#include <math.h>
#include <stdint.h>

namespace {

constexpr int Bc = 16, Nc = 1024, Ec = 128, Hc = 8, KDc = 16, HKc = 128;
// 1/sqrt(KD) * log2(e): fold softmax scale + base-2 conversion into Q
constexpr float SCALE = 0.25f * 1.4426950408889634f;

typedef __attribute__((ext_vector_type(8))) short short8;
typedef __attribute__((ext_vector_type(16))) float f32x16;
typedef __attribute__((ext_vector_type(4))) int int4v;

__device__ inline uint16_t f2bf(float f) {
  __hip_bfloat16 h = __float2bfloat16(f);
  uint16_t s; __builtin_memcpy(&s, &h, 2);
  return s;
}

__device__ inline short8 as_s8(int4v v) {
  short8 r; __builtin_memcpy(&r, &v, 16); return r;
}

// ---------------- Kernel 1: fused QKV projection + adjacency bit-pack ----------------
// (round-3 source exactly: scalar-broadcast loop, pack unroll 4 — measured ~33 us)
__global__ __launch_bounds__(256) void qkv_kernel(
    const float* __restrict__ hin,
    const float* __restrict__ Wq, const float* __restrict__ Wk, const float* __restrict__ Wv,
    const int* __restrict__ adj,
    uint16_t* __restrict__ Qf, uint16_t* __restrict__ Kf, uint16_t* __restrict__ Vf,
    uint32_t* __restrict__ bits)
{
  __shared__ float h_lds[16][Ec];
  const int t = threadIdx.x;
  const int row0 = blockIdx.x * 16;

  const float4* hsrc = reinterpret_cast<const float4*>(hin + (size_t)row0 * Ec);
  float4* hdst = reinterpret_cast<float4*>(&h_lds[0][0]);
  hdst[t] = hsrc[t]; hdst[t + 256] = hsrc[t + 256];

  // ---- adjacency bit-pack (overlaps with h staging / other waves' VALU) ----
  {
    const int gw = blockIdx.x * 4 + (t >> 6);   // global wave id, 4096 waves
    const int l = t & 63;
    const int* asrc = adj + (size_t)gw * 4096 + l;   // 64 chunks x 64 ints
    uint2* bdst = reinterpret_cast<uint2*>(bits) + (size_t)gw * 64;
    #pragma unroll 4
    for (int c = 0; c < 64; ++c) {
      const int v = asrc[(size_t)c * 64];
      const unsigned long long m = __ballot(v != 0);
      if (l == 0) bdst[c] = make_uint2((uint32_t)m, (uint32_t)(m >> 32));
    }
  }
  __syncthreads();

  const int c = t & 127, rg = t >> 7;
  const int head = c >> 4, kd = c & 15;
  const float* wq = Wq + head * (Ec * KDc) + kd;
  const float* wk = Wk + head * (Ec * KDc) + kd;
  const float* wv = Wv + head * (Ec * KDc) + kd;

  float aq[8], ak[8], av[8];
  #pragma unroll
  for (int r = 0; r < 8; ++r) { aq[r] = 0.f; ak[r] = 0.f; av[r] = 0.f; }

  #pragma unroll 4
  for (int e = 0; e < Ec; ++e) {
    const float q_ = wq[e * KDc];
    const float k_ = wk[e * KDc];
    const float v_ = wv[e * KDc];
    #pragma unroll
    for (int r = 0; r < 8; ++r) {
      const float hv = h_lds[rg * 8 + r][e];   // LDS broadcast within wave
      aq[r] = fmaf(hv, q_, aq[r]);
      ak[r] = fmaf(hv, k_, ak[r]);
      av[r] = fmaf(hv, v_, av[r]);
    }
  }

  const int b = row0 >> 10;
  const int h5 = (kd >> 2) & 1;
  const int elem = (kd & 3) + 4 * (kd >> 3);

  #pragma unroll
  for (int r = 0; r < 8; ++r) {
    const int n = (row0 & 1023) + rg * 8 + r;
    const int blk = n >> 5;
    const int lane = (n & 31) + 32 * h5;
    const size_t qkoff = ((((size_t)b * Hc + head) * 32 + blk) * 64 + lane) * 8 + elem;
    Qf[qkoff] = f2bf(aq[r] * SCALE);
    Kf[qkoff] = f2bf(ak[r]);
    const int half = (n >> 4) & 1, krow = n & 15;
    const int h5v = (krow >> 2) & 1;
    const int iv = (krow & 3) + 4 * (krow >> 3);
    const int lid = kd + 16 * h5v;
    const size_t voff = (((((size_t)b * Hc + head) * 32 + blk) * 2 + half) * 32 + lid) * 8 + iv;
    Vf[voff] = f2bf(av[r]);
  }
}

// ---------------- Kernel 2: MFMA masked flash attention + out-proj ----------------
// Explicit register double-buffer: loads for iter mb+1 issue before compute of mb.
// V loads are unconditional (clamped address) + cndmask-merged constants, so the
// pipeline has no divergent loads. setprio(1) around the PV MFMA pair (T5).
__global__ __launch_bounds__(1024, 4) void attn_kernel(
    const uint16_t* __restrict__ Qf, const uint16_t* __restrict__ Kf,
    const uint16_t* __restrict__ Vf, const uint32_t* __restrict__ bits,
    const float* __restrict__ hin, const float* __restrict__ Wout,
    float* __restrict__ out)
{
  __shared__ uint32_t adj_lds[32][33];   // [q-row][word], padded
  __shared__ float heads[32][132];       // [q-row][h*16+kd], padded
  __shared__ float S_lds[8][32];         // [head][q-row]

  const int t = threadIdx.x;
  // XCD-aware swizzle: 512 blocks, 64 per XCD -> each XCD sees 2 batches' K/V
  const int bid = blockIdx.x;
  const int swz = (bid & 7) * 64 + (bid >> 3);
  const int b = swz >> 5;
  const int qblk = swz & 31;
  const int w = t >> 6, hd = w & 7, hs = w >> 3;
  const int l = t & 63, h5 = l >> 5, q = l & 31;

  // stage adjacency bit words: 32 rows x 32 words, fully coalesced
  adj_lds[t >> 5][t & 31] =
      bits[((size_t)b * Nc + qblk * 32 + (t >> 5)) * 32 + (t & 31)];

  const short8 qfrag = *reinterpret_cast<const short8*>(
      Qf + ((((size_t)b * Hc + hd) * 32 + qblk) * 64 + l) * 8);

  __syncthreads();

  f32x16 acc, zc;
  #pragma unroll
  for (int i = 0; i < 16; ++i) { acc[i] = 0.f; zc[i] = 0.f; }

  const uint16_t* kbase = Kf + (((size_t)b * Hc + hd) * 32 + hs * 16) * 512 + (size_t)l * 8;
  // clamped V address: valid for ALL lanes; junk lanes re-read valid lines
  const uint16_t* vbase = Vf + (((size_t)b * Hc + hd) * 32 + hs * 16) * 512
                             + (size_t)((q & 15) + 16 * h5) * 8;

  // constant B-operand lanes: col 16 = ones (S column), cols 17..31 = zeros
  int4v vconst;
  #pragma unroll
  for (int i = 0; i < 4; ++i) vconst[i] = (q == 16) ? 0x3F803F80 : 0;
  const bool vld = (q < 16);

  // ---- prologue: issue loads for mb = 0 ----
  int4v kf_n = *reinterpret_cast<const int4v*>(kbase);
  int4v v0_n = *reinterpret_cast<const int4v*>(vbase);
  int4v v1_n = *reinterpret_cast<const int4v*>(vbase + 256);

  #pragma unroll 2
  for (int mb = 0; mb < 16; ++mb) {
    const int4v kf_c = kf_n;
    const int4v v0_c = v0_n, v1_c = v1_n;
    if (mb < 15) {   // issue next-iteration loads before compute of this one
      const uint16_t* kp = kbase + (size_t)(mb + 1) * 512;
      const uint16_t* vp = vbase + (size_t)(mb + 1) * 512;
      kf_n = *reinterpret_cast<const int4v*>(kp);
      v0_n = *reinterpret_cast<const int4v*>(vp);
      v1_n = *reinterpret_cast<const int4v*>(vp + 256);
    }

    f32x16 s = __builtin_amdgcn_mfma_f32_32x32x16_bf16(as_s8(kf_c), qfrag, zc, 0, 0, 0);

    const uint32_t wsh = adj_lds[q][hs * 16 + mb] >> (4 * h5);
    float p[16];
    #pragma unroll
    for (int r = 0; r < 16; ++r) {
      const float e = __builtin_amdgcn_exp2f(s[r]);   // fixed-M: scores bounded
      const uint32_t lm = (uint32_t)__builtin_amdgcn_sbfe(
          (int)wsh, (r & 3) + 8 * (r >> 2), 1);        // 0 or 0xFFFFFFFF
      p[r] = __uint_as_float(__float_as_uint(e) & lm);
    }

    short8 pa0, pa1;
    #pragma unroll
    for (int i = 0; i < 8; ++i) { pa0[i] = (short)f2bf(p[i]); pa1[i] = (short)f2bf(p[i + 8]); }

    // merge constant lanes (4+4 cndmask)
    int4v v0i, v1i;
    #pragma unroll
    for (int i = 0; i < 4; ++i) {
      v0i[i] = vld ? v0_c[i] : vconst[i];
      v1i[i] = vld ? v1_c[i] : vconst[i];
    }

    __builtin_amdgcn_s_setprio(1);
    acc = __builtin_amdgcn_mfma_f32_32x32x16_bf16(pa0, as_s8(v0i), acc, 0, 0, 0);
    acc = __builtin_amdgcn_mfma_f32_32x32x16_bf16(pa1, as_s8(v1i), acc, 0, 0, 0);
    __builtin_amdgcn_s_setprio(0);
  }

  // ---- combine key-halves through LDS; S sits in acc of q==16 lanes ----
  if (hs == 0) {
    if (q < 16) {
      #pragma unroll
      for (int r = 0; r < 16; ++r)
        heads[(r & 3) + 8 * (r >> 2) + 4 * h5][hd * 16 + q] = acc[r];
    } else if (q == 16) {
      #pragma unroll
      for (int r = 0; r < 16; ++r)
        S_lds[hd][(r & 3) + 8 * (r >> 2) + 4 * h5] = acc[r];
    }
  }
  __syncthreads();
  if (hs == 1) {
    if (q < 16) {
      #pragma unroll
      for (int r = 0; r < 16; ++r)
        heads[(r & 3) + 8 * (r >> 2) + 4 * h5][hd * 16 + q] += acc[r];
    } else if (q == 16) {
      #pragma unroll
      for (int r = 0; r < 16; ++r)
        S_lds[hd][(r & 3) + 8 * (r >> 2) + 4 * h5] += acc[r];
    }
  }
  __syncthreads();
  if (t < 256) S_lds[t >> 5][t & 31] = 1.0f / S_lds[t >> 5][t & 31];
  __syncthreads();
  #pragma unroll
  for (int i = 0; i < 4; ++i) {
    const int idx = t + i * 1024;
    const int rr = idx >> 7, cc = idx & 127;
    heads[rr][cc] *= S_lds[cc >> 4][rr];
  }
  __syncthreads();

  // ---- output projection + residual: thread = (q2 = t>>5, eg = t&31 -> 4 e-cols) ----
  const int q2 = t >> 5, eg = t & 31;
  const size_t orow = (size_t)b * Nc + qblk * 32 + q2;
  float4 o = *(reinterpret_cast<const float4*>(hin + orow * Ec) + eg);
  #pragma unroll 4
  for (int hk = 0; hk < HKc; ++hk) {
    const float hv = heads[q2][hk];                       // 32-lane broadcast
    const float4 wv4 = *(reinterpret_cast<const float4*>(Wout + (size_t)hk * Ec) + eg);
    o.x = fmaf(hv, wv4.x, o.x); o.y = fmaf(hv, wv4.y, o.y);
    o.z = fmaf(hv, wv4.z, o.z); o.w = fmaf(hv, wv4.w, o.w);
  }
  *(reinterpret_cast<float4*>(out + orow * Ec) + eg) = o;
}

} // namespace

extern "C" void kernel_launch(void* const* d_in, const int* in_sizes, int n_in,
                              void* d_out, int out_size, void* d_ws, size_t ws_size,
                              hipStream_t stream) {
  (void)in_sizes; (void)n_in; (void)out_size; (void)ws_size;
  const float* h   = (const float*)d_in[0];
  const int*   adj = (const int*)d_in[1];
  const float* Wq  = (const float*)d_in[2];
  const float* Wk  = (const float*)d_in[3];
  const float* Wv  = (const float*)d_in[4];
  const float* Wo  = (const float*)d_in[5];
  float* out = (float*)d_out;

  // workspace: Qf/Kf/Vf bf16 fragment buffers (4 MB each) + adjacency bits (2 MB)
  uint16_t* Qf = (uint16_t*)d_ws;
  uint16_t* Kf = Qf + (size_t)Bc * Hc * Nc * KDc;
  uint16_t* Vf = Kf + (size_t)Bc * Hc * Nc * KDc;
  uint32_t* bits = (uint32_t*)(Vf + (size_t)Bc * Hc * Nc * KDc);

  qkv_kernel<<<Bc * Nc / 16, 256, 0, stream>>>(h, Wq, Wk, Wv, adj, Qf, Kf, Vf, bits);
  attn_kernel<<<Bc * (Nc / 32), 1024, 0, stream>>>(Qf, Kf, Vf, bits, h, Wo, out);
}

// Round 8
// 107.165 us; speedup vs baseline: 1.2806x; 1.0599x over previous
//
#include <hip/hip_runtime.h>
#include <hip/hip_bf16.h>
#include <math.h>
#include <stdint.h>

namespace {

constexpr int Bc = 16, Nc = 1024, Ec = 128, Hc = 8, KDc = 16, HKc = 128;
// 1/sqrt(KD) * log2(e): fold softmax scale + base-2 conversion into Q
constexpr float SCALE = 0.25f * 1.4426950408889634f;

typedef __attribute__((ext_vector_type(4))) short short4v;
typedef __attribute__((ext_vector_type(8))) short short8;
typedef __attribute__((ext_vector_type(4))) float f32x4;
typedef __attribute__((ext_vector_type(4))) int int4v;

__device__ inline uint16_t f2bf(float f) {
  __hip_bfloat16 h = __float2bfloat16(f);
  uint16_t s; __builtin_memcpy(&s, &h, 2);
  return s;
}

// packed f32->bf16 (T12 recipe: no builtin on gfx950; single VALU op for 2 values)
__device__ inline uint32_t cvt_pk_bf16(float a, float b) {
  uint32_t r;
  asm("v_cvt_pk_bf16_f32 %0, %1, %2" : "=v"(r) : "v"(a), "v"(b));
  return r;
}

// masked exp2: p = exp2(s) if adjacency bit set else 0  (sbfe -> 0/-1 mask)
__device__ inline float mexp(float s, uint32_t w, int bit) {
  const uint32_t m = (uint32_t)__builtin_amdgcn_sbfe((int)w, bit, 1);
  return __uint_as_float(__float_as_uint(__builtin_amdgcn_exp2f(s)) & m);
}

// ---------------- Kernel 1: fused QKV projection + adjacency bit-pack ----------------
// r3 structure (validated); only the fragment write layouts changed for 16x16 MFMA:
//  Q [b][h][qtile64][lane64][4]: lane=(n&15)+16*(kd>>2), elem=kd&3
//  K [b][h][kblk32][lane64][8]: lane=(n&15)+16*(kd>>2), elem=(kd&3)+4*((n>>4)&1)
//  V [b][h][kblk32][lane64][8]: lane=kd+16*((n>>2)&3), elem=(n&3)+4*((n>>4)&1)
__global__ __launch_bounds__(256) void qkv_kernel(
    const float* __restrict__ hin,
    const float* __restrict__ Wq, const float* __restrict__ Wk, const float* __restrict__ Wv,
    const int* __restrict__ adj,
    uint16_t* __restrict__ Qf, uint16_t* __restrict__ Kf, uint16_t* __restrict__ Vf,
    uint32_t* __restrict__ bits)
{
  __shared__ float h_lds[16][Ec];
  const int t = threadIdx.x;
  const int row0 = blockIdx.x * 16;

  const float4* hsrc = reinterpret_cast<const float4*>(hin + (size_t)row0 * Ec);
  float4* hdst = reinterpret_cast<float4*>(&h_lds[0][0]);
  hdst[t] = hsrc[t]; hdst[t + 256] = hsrc[t + 256];

  // ---- adjacency bit-pack (overlaps with h staging / other waves' VALU) ----
  {
    const int gw = blockIdx.x * 4 + (t >> 6);   // global wave id, 4096 waves
    const int l = t & 63;
    const int* asrc = adj + (size_t)gw * 4096 + l;   // 64 chunks x 64 ints
    uint2* bdst = reinterpret_cast<uint2*>(bits) + (size_t)gw * 64;
    #pragma unroll 4
    for (int c = 0; c < 64; ++c) {
      const int v = asrc[(size_t)c * 64];
      const unsigned long long m = __ballot(v != 0);
      if (l == 0) bdst[c] = make_uint2((uint32_t)m, (uint32_t)(m >> 32));
    }
  }
  __syncthreads();

  const int c = t & 127, rg = t >> 7;
  const int head = c >> 4, kd = c & 15;
  const float* wq = Wq + head * (Ec * KDc) + kd;
  const float* wk = Wk + head * (Ec * KDc) + kd;
  const float* wv = Wv + head * (Ec * KDc) + kd;

  float aq[8], ak[8], av[8];
  #pragma unroll
  for (int r = 0; r < 8; ++r) { aq[r] = 0.f; ak[r] = 0.f; av[r] = 0.f; }

  #pragma unroll 4
  for (int e = 0; e < Ec; ++e) {
    const float q_ = wq[e * KDc];
    const float k_ = wk[e * KDc];
    const float v_ = wv[e * KDc];
    #pragma unroll
    for (int r = 0; r < 8; ++r) {
      const float hv = h_lds[rg * 8 + r][e];   // LDS broadcast within wave
      aq[r] = fmaf(hv, q_, aq[r]);
      ak[r] = fmaf(hv, k_, ak[r]);
      av[r] = fmaf(hv, v_, av[r]);
    }
  }

  const int b = row0 >> 10;

  #pragma unroll
  for (int r = 0; r < 8; ++r) {
    const int n = (row0 & 1023) + rg * 8 + r;
    // Q fragment (B-operand of QK, 16q x 16kd tiles)
    const int qtile = (n >> 4) & 63;
    const int laneq = (n & 15) + 16 * (kd >> 2);
    const size_t qoff = ((((size_t)b * Hc + head) * 64 + qtile) * 64 + laneq) * 4 + (kd & 3);
    Qf[qoff] = f2bf(aq[r] * SCALE);
    // K fragment (A-operand of QK, 32-key blocks; elems 0-3 = keys 0-15, 4-7 = keys 16-31)
    const int kblk = n >> 5;
    const int lanek = (n & 15) + 16 * (kd >> 2);
    const int elemk = (kd & 3) + 4 * ((n >> 4) & 1);
    const size_t koff = ((((size_t)b * Hc + head) * 32 + kblk) * 64 + lanek) * 8 + elemk;
    Kf[koff] = f2bf(ak[r]);
    // V fragment (B-operand of PV, K=32 keys)
    const int lanev = kd + 16 * ((n >> 2) & 3);
    const int elemv = (n & 3) + 4 * ((n >> 4) & 1);
    const size_t voff = ((((size_t)b * Hc + head) * 32 + kblk) * 64 + lanev) * 8 + elemv;
    Vf[voff] = f2bf(av[r]);
  }
}

// ---------------- Kernel 2: 16x16-fragment MFMA masked attention + out-proj ----------
// 512 threads = 8 waves = 8 heads; block = (b, 16 q-rows); grid = 1024 blocks (4/CU).
// Per 32-key iter: QK1/QK2 (kd in k-slots 0-3, slots 4-7 zero in BOTH operands) then
// PV with K=32 keys, P fed straight from QK D-regs (col=l&15=q, row=4*(l>>4)+i=key).
__global__ __launch_bounds__(512, 8) void attn_kernel(
    const uint16_t* __restrict__ Qf, const uint16_t* __restrict__ Kf,
    const uint16_t* __restrict__ Vf, const uint32_t* __restrict__ bits,
    const float* __restrict__ hin, const float* __restrict__ Wout,
    float* __restrict__ out)
{
  __shared__ uint32_t adj_lds[16][33];   // [q-row][word], padded
  __shared__ float heads[16][132];       // [q-row][h*16+kd], padded
  __shared__ float S_lds[8][16];         // [head][q-row]

  const int t = threadIdx.x;
  // XCD-aware swizzle: 1024 blocks, 128/XCD -> each XCD owns 2 batches' K/V (~1MB in L2)
  const int bid = blockIdx.x;
  const int swz = (bid & 7) * 128 + (bid >> 3);
  const int b = swz >> 6;
  const int qblk = swz & 63;
  const int hd = t >> 6, l = t & 63;
  const int g = l >> 4, q = l & 15;

  // stage adjacency bit words: 16 rows x 32 words, one word per thread
  adj_lds[t >> 5][t & 31] =
      bits[((size_t)b * Nc + qblk * 16 + (t >> 5)) * 32 + (t & 31)];

  // Q fragment: 4 bf16 (kd = 4g+i), upper 4 k-slots zero
  const short4v q4 = *reinterpret_cast<const short4v*>(
      Qf + ((((size_t)b * Hc + hd) * 64 + qblk) * 64 + l) * 4);
  short8 qf8;
  #pragma unroll
  for (int i = 0; i < 4; ++i) { qf8[i] = q4[i]; qf8[4 + i] = 0; }

  __syncthreads();

  f32x4 acc = {0.f, 0.f, 0.f, 0.f};
  const f32x4 zc = {0.f, 0.f, 0.f, 0.f};
  float S = 0.f;

  const uint16_t* kb = Kf + (((size_t)b * Hc + hd) * 32) * 512 + (size_t)l * 8;
  const uint16_t* vb = Vf + (((size_t)b * Hc + hd) * 32) * 512 + (size_t)l * 8;

  #pragma unroll 2
  for (int kblk = 0; kblk < 32; ++kblk) {
    const short8 kf = *reinterpret_cast<const short8*>(kb + (size_t)kblk * 512);
    const short8 vf = *reinterpret_cast<const short8*>(vb + (size_t)kblk * 512);

    short8 a1, a2;
    #pragma unroll
    for (int i = 0; i < 4; ++i) {
      a1[i] = kf[i];     a1[4 + i] = 0;
      a2[i] = kf[4 + i]; a2[4 + i] = 0;
    }

    const f32x4 s0 = __builtin_amdgcn_mfma_f32_16x16x32_bf16(a1, qf8, zc, 0, 0, 0);
    const f32x4 s1 = __builtin_amdgcn_mfma_f32_16x16x32_bf16(a2, qf8, zc, 0, 0, 0);

    const uint32_t wsh = adj_lds[q][kblk] >> (4 * g);   // keys 4g+i -> bits i / 16+i

    const float p0 = mexp(s0[0], wsh, 0),  p1 = mexp(s0[1], wsh, 1);
    const float p2 = mexp(s0[2], wsh, 2),  p3 = mexp(s0[3], wsh, 3);
    const float p4 = mexp(s1[0], wsh, 16), p5 = mexp(s1[1], wsh, 17);
    const float p6 = mexp(s1[2], wsh, 18), p7 = mexp(s1[3], wsh, 19);
    S += ((p0 + p1) + (p2 + p3)) + ((p4 + p5) + (p6 + p7));

    int4v paw;
    paw[0] = (int)cvt_pk_bf16(p0, p1);
    paw[1] = (int)cvt_pk_bf16(p2, p3);
    paw[2] = (int)cvt_pk_bf16(p4, p5);
    paw[3] = (int)cvt_pk_bf16(p6, p7);
    short8 pa; __builtin_memcpy(&pa, &paw, 16);

    acc = __builtin_amdgcn_mfma_f32_16x16x32_bf16(pa, vf, acc, 0, 0, 0);
  }

  // ---- S reduce over the 4 lane-groups holding the same q ----
  S += __shfl_xor(S, 16);
  S += __shfl_xor(S, 32);

  // acc[i] = out[q=4g+i][kd=l&15] (unnormalized); park in LDS
  #pragma unroll
  for (int i = 0; i < 4; ++i) heads[4 * g + i][hd * 16 + q] = acc[i];
  if (l < 16) S_lds[hd][l] = S;
  __syncthreads();
  if (t < 128) S_lds[t >> 4][t & 15] = 1.0f / S_lds[t >> 4][t & 15];
  __syncthreads();
  #pragma unroll
  for (int i = 0; i < 4; ++i) {
    const int idx = t + i * 512;
    const int rr = idx >> 7, cc = idx & 127;
    heads[rr][cc] *= S_lds[cc >> 4][rr];
  }
  __syncthreads();

  // ---- output projection + residual: thread = (q2 = t>>5, eg = t&31 -> 4 e-cols) ----
  const int q2 = t >> 5, eg = t & 31;
  const size_t orow = (size_t)b * Nc + qblk * 16 + q2;
  float4 o = *(reinterpret_cast<const float4*>(hin + orow * Ec) + eg);
  #pragma unroll 4
  for (int hk = 0; hk < HKc; ++hk) {
    const float hv = heads[q2][hk];                       // 32-lane broadcast
    const float4 wv4 = *(reinterpret_cast<const float4*>(Wout + (size_t)hk * Ec) + eg);
    o.x = fmaf(hv, wv4.x, o.x); o.y = fmaf(hv, wv4.y, o.y);
    o.z = fmaf(hv, wv4.z, o.z); o.w = fmaf(hv, wv4.w, o.w);
  }
  *(reinterpret_cast<float4*>(out + orow * Ec) + eg) = o;
}

} // namespace

extern "C" void kernel_launch(void* const* d_in, const int* in_sizes, int n_in,
                              void* d_out, int out_size, void* d_ws, size_t ws_size,
                              hipStream_t stream) {
  (void)in_sizes; (void)n_in; (void)out_size; (void)ws_size;
  const float* h   = (const float*)d_in[0];
  const int*   adj = (const int*)d_in[1];
  const float* Wq  = (const float*)d_in[2];
  const float* Wk  = (const float*)d_in[3];
  const float* Wv  = (const float*)d_in[4];
  const float* Wo  = (const float*)d_in[5];
  float* out = (float*)d_out;

  // workspace: Qf/Kf/Vf bf16 fragment buffers (4 MB each) + adjacency bits (2 MB)
  uint16_t* Qf = (uint16_t*)d_ws;
  uint16_t* Kf = Qf + (size_t)Bc * Hc * Nc * KDc;
  uint16_t* Vf = Kf + (size_t)Bc * Hc * Nc * KDc;
  uint32_t* bits = (uint32_t*)(Vf + (size_t)Bc * Hc * Nc * KDc);

  qkv_kernel<<<Bc * Nc / 16, 256, 0, stream>>>(h, Wq, Wk, Wv, adj, Qf, Kf, Vf, bits);
  attn_kernel<<<Bc * (Nc / 16), 512, 0, stream>>>(Qf, Kf, Vf, bits, h, Wo, out);
}

// Round 10
// 90.988 us; speedup vs baseline: 1.5082x; 1.1778x over previous
//
#include <hip/hip_runtime.h>
#include <hip/hip_bf16.h>
#include <math.h>
#include <stdint.h>

namespace {

constexpr int Bc = 16, Nc = 1024, Ec = 128, Hc = 8, KDc = 16, HKc = 128;
// 1/sqrt(KD) * log2(e): fold softmax scale + base-2 conversion into Q
constexpr float SCALE = 0.25f * 1.4426950408889634f;

typedef __attribute__((ext_vector_type(4))) short short4v;
typedef __attribute__((ext_vector_type(8))) short short8;
typedef __attribute__((ext_vector_type(4))) float f32x4;
typedef __attribute__((ext_vector_type(4))) int int4v;

__device__ inline uint16_t f2bf(float f) {
  __hip_bfloat16 h = __float2bfloat16(f);
  uint16_t s; __builtin_memcpy(&s, &h, 2);
  return s;
}

// RNE pair pack for output stores (matches r8's output quantization path)
__device__ inline uint32_t pk2(float a, float b) {
  return (uint32_t)f2bf(a) | ((uint32_t)f2bf(b) << 16);
}

// packed f32->bf16 (attn P-values only, as in r8)
__device__ inline uint32_t cvt_pk_bf16(float a, float b) {
  uint32_t r;
  asm("v_cvt_pk_bf16_f32 %0, %1, %2" : "=v"(r) : "v"(a), "v"(b));
  return r;
}

// masked exp2: p = exp2(s) if adjacency bit set else 0  (sbfe -> 0/-1 mask)
__device__ inline float mexp(float s, uint32_t w, int bit) {
  const uint32_t m = (uint32_t)__builtin_amdgcn_sbfe((int)w, bit, 1);
  return __uint_as_float(__float_as_uint(__builtin_amdgcn_exp2f(s)) & m);
}

// hi/lo split: x ~= hi + lo, both bf16 RNE -> MFMA pair-products restore ~fp32 accuracy
__device__ inline void split8(const float* x, short8& hi, short8& lo) {
  #pragma unroll
  for (int i = 0; i < 8; ++i) {
    const uint16_t h = f2bf(x[i]);
    hi[i] = (short)h;
    lo[i] = (short)f2bf(x[i] - __uint_as_float((uint32_t)h << 16));
  }
}
__device__ inline short8 round8(const float* x) {
  short8 r;
  #pragma unroll
  for (int i = 0; i < 8; ++i) r[i] = (short)f2bf(x[i]);
  return r;
}

// ---------------- Kernel 1: MFMA QKV projection (hi/lo split) + bitpack ----------------
// 512 threads = 8 waves = 8 heads; block = 32 tokens; grid = 512.
// Q/K: D[kd][token] = (Whi+Wlo)^T (hhi+hlo), 3 MFMAs (lo*lo dropped, ~2^-18).
// V:   D[key][kd] = (hhi+hlo) Wv, 2 MFMAs. Same h fragments serve both operand roles.
// Fragment layouts = r8's (validated): stores are lane-local D regs, coalesced.
__global__ __launch_bounds__(512) void qkv_kernel(
    const float* __restrict__ hin,
    const float* __restrict__ Wq, const float* __restrict__ Wk, const float* __restrict__ Wv,
    const int* __restrict__ adj,
    uint16_t* __restrict__ Qf, uint16_t* __restrict__ Kf, uint16_t* __restrict__ Vf,
    uint32_t* __restrict__ bits)
{
  const int t = threadIdx.x;
  const int hd = t >> 6;            // wave = head
  const int l = t & 63;
  const int g = l >> 4, c = l & 15;

  // ---- adjacency bit-pack (r3-validated inner code; 8 waves/block, 4 rows/wave) ----
  {
    const int gw = blockIdx.x * 8 + hd;              // 4096 waves
    const int* asrc = adj + (size_t)gw * 4096 + l;   // 64 chunks x 64 ints
    uint2* bdst = reinterpret_cast<uint2*>(bits) + (size_t)gw * 64;
    #pragma unroll 4
    for (int cc = 0; cc < 64; ++cc) {
      const unsigned long long m = __ballot(asrc[(size_t)cc * 64] != 0);
      if (l == 0) bdst[cc] = make_uint2((uint32_t)m, (uint32_t)(m >> 32));
    }
  }

  const int tokenblk = blockIdx.x;  // 32 tokens per block
  const int b = tokenblk >> 5;
  const int kblk = tokenblk & 31;

  f32x4 Qa0 = {0,0,0,0}, Qa1 = {0,0,0,0};
  f32x4 Ka0 = {0,0,0,0}, Ka1 = {0,0,0,0};
  f32x4 Va0 = {0,0,0,0}, Va1 = {0,0,0,0};

  #pragma unroll
  for (int s = 0; s < 4; ++s) {
    // W fragments: lane holds W[e = s*32 + 4g + {0..3, 16..19}][c]
    const int ebase = (s * 32 + 4 * g) * 16 + c;
    const float* wqp = Wq + hd * 2048 + ebase;
    const float* wkp = Wk + hd * 2048 + ebase;
    const float* wvp = Wv + hd * 2048 + ebase;
    float wx[8];
    short8 wqh, wql, wkh, wkl, wv8;
    wx[0]=wqp[0]; wx[1]=wqp[16]; wx[2]=wqp[32]; wx[3]=wqp[48];
    wx[4]=wqp[256]; wx[5]=wqp[272]; wx[6]=wqp[288]; wx[7]=wqp[304];
    split8(wx, wqh, wql);
    wx[0]=wkp[0]; wx[1]=wkp[16]; wx[2]=wkp[32]; wx[3]=wkp[48];
    wx[4]=wkp[256]; wx[5]=wkp[272]; wx[6]=wkp[288]; wx[7]=wkp[304];
    split8(wx, wkh, wkl);
    wx[0]=wvp[0]; wx[1]=wvp[16]; wx[2]=wvp[32]; wx[3]=wvp[48];
    wx[4]=wvp[256]; wx[5]=wvp[272]; wx[6]=wvp[288]; wx[7]=wvp[304];
    wv8 = round8(wx);

    #pragma unroll
    for (int tile = 0; tile < 2; ++tile) {
      const size_t grow = (size_t)tokenblk * 32 + tile * 16 + c;
      const float4 lo4 = *reinterpret_cast<const float4*>(hin + grow * 128 + s * 32 + 4 * g);
      const float4 hi4 = *reinterpret_cast<const float4*>(hin + grow * 128 + s * 32 + 16 + 4 * g);
      float hx[8];
      hx[0]=lo4.x; hx[1]=lo4.y; hx[2]=lo4.z; hx[3]=lo4.w;
      hx[4]=hi4.x; hx[5]=hi4.y; hx[6]=hi4.z; hx[7]=hi4.w;
      short8 hh, hl; split8(hx, hh, hl);

      if (tile == 0) {
        Qa0 = __builtin_amdgcn_mfma_f32_16x16x32_bf16(wqh, hh, Qa0, 0, 0, 0);
        Qa0 = __builtin_amdgcn_mfma_f32_16x16x32_bf16(wqh, hl, Qa0, 0, 0, 0);
        Qa0 = __builtin_amdgcn_mfma_f32_16x16x32_bf16(wql, hh, Qa0, 0, 0, 0);
        Ka0 = __builtin_amdgcn_mfma_f32_16x16x32_bf16(wkh, hh, Ka0, 0, 0, 0);
        Ka0 = __builtin_amdgcn_mfma_f32_16x16x32_bf16(wkh, hl, Ka0, 0, 0, 0);
        Ka0 = __builtin_amdgcn_mfma_f32_16x16x32_bf16(wkl, hh, Ka0, 0, 0, 0);
        Va0 = __builtin_amdgcn_mfma_f32_16x16x32_bf16(hh, wv8, Va0, 0, 0, 0);
        Va0 = __builtin_amdgcn_mfma_f32_16x16x32_bf16(hl, wv8, Va0, 0, 0, 0);
      } else {
        Qa1 = __builtin_amdgcn_mfma_f32_16x16x32_bf16(wqh, hh, Qa1, 0, 0, 0);
        Qa1 = __builtin_amdgcn_mfma_f32_16x16x32_bf16(wqh, hl, Qa1, 0, 0, 0);
        Qa1 = __builtin_amdgcn_mfma_f32_16x16x32_bf16(wql, hh, Qa1, 0, 0, 0);
        Ka1 = __builtin_amdgcn_mfma_f32_16x16x32_bf16(wkh, hh, Ka1, 0, 0, 0);
        Ka1 = __builtin_amdgcn_mfma_f32_16x16x32_bf16(wkh, hl, Ka1, 0, 0, 0);
        Ka1 = __builtin_amdgcn_mfma_f32_16x16x32_bf16(wkl, hh, Ka1, 0, 0, 0);
        Va1 = __builtin_amdgcn_mfma_f32_16x16x32_bf16(hh, wv8, Va1, 0, 0, 0);
        Va1 = __builtin_amdgcn_mfma_f32_16x16x32_bf16(hl, wv8, Va1, 0, 0, 0);
      }
    }
  }

  // ---- stores: D regs land in the producing lane (layouts = r8-validated) ----
  const int qt0 = kblk * 2;
  {
    uint2 q0, q1;
    q0.x = pk2(Qa0[0] * SCALE, Qa0[1] * SCALE);
    q0.y = pk2(Qa0[2] * SCALE, Qa0[3] * SCALE);
    q1.x = pk2(Qa1[0] * SCALE, Qa1[1] * SCALE);
    q1.y = pk2(Qa1[2] * SCALE, Qa1[3] * SCALE);
    uint16_t* qp = Qf + ((((size_t)b * Hc + hd) * 64 + qt0) * 64 + l) * 4;
    *reinterpret_cast<uint2*>(qp) = q0;
    *reinterpret_cast<uint2*>(qp + 256) = q1;
  }
  {
    int4v kw;
    kw[0] = (int)pk2(Ka0[0], Ka0[1]); kw[1] = (int)pk2(Ka0[2], Ka0[3]);
    kw[2] = (int)pk2(Ka1[0], Ka1[1]); kw[3] = (int)pk2(Ka1[2], Ka1[3]);
    *reinterpret_cast<int4v*>(Kf + ((((size_t)b * Hc + hd) * 32 + kblk) * 64 + l) * 8) = kw;
    int4v vw;
    vw[0] = (int)pk2(Va0[0], Va0[1]); vw[1] = (int)pk2(Va0[2], Va0[3]);
    vw[2] = (int)pk2(Va1[0], Va1[1]); vw[3] = (int)pk2(Va1[2], Va1[3]);
    *reinterpret_cast<int4v*>(Vf + ((((size_t)b * Hc + hd) * 32 + kblk) * 64 + l) * 8) = vw;
  }
}

// ---------------- Kernel 2: 16x16-fragment MFMA masked attention + out-proj ----------
// BYTE-IDENTICAL to round 8 (validated, ~31 us): bits-staged adjacency.
__global__ __launch_bounds__(512, 8) void attn_kernel(
    const uint16_t* __restrict__ Qf, const uint16_t* __restrict__ Kf,
    const uint16_t* __restrict__ Vf, const uint32_t* __restrict__ bits,
    const float* __restrict__ hin, const float* __restrict__ Wout,
    float* __restrict__ out)
{
  __shared__ uint32_t adj_lds[16][33];   // [q-row][word], padded
  __shared__ float heads[16][132];       // [q-row][h*16+kd], padded
  __shared__ float S_lds[8][16];         // [head][q-row]

  const int t = threadIdx.x;
  // XCD-aware swizzle: 1024 blocks, 128/XCD
  const int bid = blockIdx.x;
  const int swz = (bid & 7) * 128 + (bid >> 3);
  const int b = swz >> 6;
  const int qblk = swz & 63;
  const int hd = t >> 6, l = t & 63;
  const int g = l >> 4, q = l & 15;

  // stage adjacency bit words: 16 rows x 32 words, fully coalesced
  adj_lds[t >> 5][t & 31] =
      bits[((size_t)b * Nc + qblk * 16 + (t >> 5)) * 32 + (t & 31)];

  // Q fragment: 4 bf16 (kd = 4g+i), upper 4 k-slots zero
  const short4v q4 = *reinterpret_cast<const short4v*>(
      Qf + ((((size_t)b * Hc + hd) * 64 + qblk) * 64 + l) * 4);
  short8 qf8;
  #pragma unroll
  for (int i = 0; i < 4; ++i) { qf8[i] = q4[i]; qf8[4 + i] = 0; }

  __syncthreads();

  f32x4 acc = {0.f, 0.f, 0.f, 0.f};
  const f32x4 zc = {0.f, 0.f, 0.f, 0.f};
  float S = 0.f;

  const uint16_t* kb = Kf + (((size_t)b * Hc + hd) * 32) * 512 + (size_t)l * 8;
  const uint16_t* vb = Vf + (((size_t)b * Hc + hd) * 32) * 512 + (size_t)l * 8;

  #pragma unroll 2
  for (int kblk = 0; kblk < 32; ++kblk) {
    const short8 kf = *reinterpret_cast<const short8*>(kb + (size_t)kblk * 512);
    const short8 vf = *reinterpret_cast<const short8*>(vb + (size_t)kblk * 512);

    short8 a1, a2;
    #pragma unroll
    for (int i = 0; i < 4; ++i) {
      a1[i] = kf[i];     a1[4 + i] = 0;
      a2[i] = kf[4 + i]; a2[4 + i] = 0;
    }

    const f32x4 s0 = __builtin_amdgcn_mfma_f32_16x16x32_bf16(a1, qf8, zc, 0, 0, 0);
    const f32x4 s1 = __builtin_amdgcn_mfma_f32_16x16x32_bf16(a2, qf8, zc, 0, 0, 0);

    const uint32_t wsh = adj_lds[q][kblk] >> (4 * g);   // keys 4g+i -> bits i / 16+i

    const float p0 = mexp(s0[0], wsh, 0),  p1 = mexp(s0[1], wsh, 1);
    const float p2 = mexp(s0[2], wsh, 2),  p3 = mexp(s0[3], wsh, 3);
    const float p4 = mexp(s1[0], wsh, 16), p5 = mexp(s1[1], wsh, 17);
    const float p6 = mexp(s1[2], wsh, 18), p7 = mexp(s1[3], wsh, 19);
    S += ((p0 + p1) + (p2 + p3)) + ((p4 + p5) + (p6 + p7));

    int4v paw;
    paw[0] = (int)cvt_pk_bf16(p0, p1);
    paw[1] = (int)cvt_pk_bf16(p2, p3);
    paw[2] = (int)cvt_pk_bf16(p4, p5);
    paw[3] = (int)cvt_pk_bf16(p6, p7);
    short8 pa; __builtin_memcpy(&pa, &paw, 16);

    acc = __builtin_amdgcn_mfma_f32_16x16x32_bf16(pa, vf, acc, 0, 0, 0);
  }

  // ---- S reduce over the 4 lane-groups holding the same q ----
  S += __shfl_xor(S, 16);
  S += __shfl_xor(S, 32);

  // acc[i] = out[q=4g+i][kd=l&15] (unnormalized); park in LDS
  #pragma unroll
  for (int i = 0; i < 4; ++i) heads[4 * g + i][hd * 16 + q] = acc[i];
  if (l < 16) S_lds[hd][l] = S;
  __syncthreads();
  if (t < 128) S_lds[t >> 4][t & 15] = 1.0f / S_lds[t >> 4][t & 15];
  __syncthreads();
  #pragma unroll
  for (int i = 0; i < 4; ++i) {
    const int idx = t + i * 512;
    const int rr = idx >> 7, cc = idx & 127;
    heads[rr][cc] *= S_lds[cc >> 4][rr];
  }
  __syncthreads();

  // ---- output projection + residual: thread = (q2 = t>>5, eg = t&31 -> 4 e-cols) ----
  const int q2 = t >> 5, eg = t & 31;
  const size_t orow = (size_t)b * Nc + qblk * 16 + q2;
  float4 o = *(reinterpret_cast<const float4*>(hin + orow * Ec) + eg);
  #pragma unroll 4
  for (int hk = 0; hk < HKc; ++hk) {
    const float hv = heads[q2][hk];                       // 32-lane broadcast
    const float4 wv4 = *(reinterpret_cast<const float4*>(Wout + (size_t)hk * Ec) + eg);
    o.x = fmaf(hv, wv4.x, o.x); o.y = fmaf(hv, wv4.y, o.y);
    o.z = fmaf(hv, wv4.z, o.z); o.w = fmaf(hv, wv4.w, o.w);
  }
  *(reinterpret_cast<float4*>(out + orow * Ec) + eg) = o;
}

} // namespace

extern "C" void kernel_launch(void* const* d_in, const int* in_sizes, int n_in,
                              void* d_out, int out_size, void* d_ws, size_t ws_size,
                              hipStream_t stream) {
  (void)in_sizes; (void)n_in; (void)out_size; (void)ws_size;
  const float* h   = (const float*)d_in[0];
  const int*   adj = (const int*)d_in[1];
  const float* Wq  = (const float*)d_in[2];
  const float* Wk  = (const float*)d_in[3];
  const float* Wv  = (const float*)d_in[4];
  const float* Wo  = (const float*)d_in[5];
  float* out = (float*)d_out;

  // workspace: Qf/Kf/Vf bf16 fragment buffers (4 MB each) + adjacency bits (2 MB)
  uint16_t* Qf = (uint16_t*)d_ws;
  uint16_t* Kf = Qf + (size_t)Bc * Hc * Nc * KDc;
  uint16_t* Vf = Kf + (size_t)Bc * Hc * Nc * KDc;
  uint32_t* bits = (uint32_t*)(Vf + (size_t)Bc * Hc * Nc * KDc);

  qkv_kernel<<<Bc * Nc / 32, 512, 0, stream>>>(h, Wq, Wk, Wv, adj, Qf, Kf, Vf, bits);
  attn_kernel<<<Bc * (Nc / 16), 512, 0, stream>>>(Qf, Kf, Vf, bits, h, Wo, out);
}

// Round 11
// 86.672 us; speedup vs baseline: 1.5833x; 1.0498x over previous
//
#include <hip/hip_runtime.h>
#include <hip/hip_bf16.h>
#include <math.h>
#include <stdint.h>

namespace {

constexpr int Bc = 16, Nc = 1024, Ec = 128, Hc = 8, KDc = 16, HKc = 128;
// 1/sqrt(KD) * log2(e): fold softmax scale + base-2 conversion into Q
constexpr float SCALE = 0.25f * 1.4426950408889634f;

typedef __attribute__((ext_vector_type(4))) short short4v;
typedef __attribute__((ext_vector_type(8))) short short8;
typedef __attribute__((ext_vector_type(4))) float f32x4;
typedef __attribute__((ext_vector_type(4))) int int4v;

__device__ inline uint16_t f2bf(float f) {
  __hip_bfloat16 h = __float2bfloat16(f);
  uint16_t s; __builtin_memcpy(&s, &h, 2);
  return s;
}

// RNE pair pack for output stores
__device__ inline uint32_t pk2(float a, float b) {
  return (uint32_t)f2bf(a) | ((uint32_t)f2bf(b) << 16);
}

// packed f32->bf16 (attn P-values only)
__device__ inline uint32_t cvt_pk_bf16(float a, float b) {
  uint32_t r;
  asm("v_cvt_pk_bf16_f32 %0, %1, %2" : "=v"(r) : "v"(a), "v"(b));
  return r;
}

// masked exp2: p = exp2(s) if adjacency bit set else 0  (sbfe -> 0/-1 mask)
__device__ inline float mexp(float s, uint32_t w, int bit) {
  const uint32_t m = (uint32_t)__builtin_amdgcn_sbfe((int)w, bit, 1);
  return __uint_as_float(__float_as_uint(__builtin_amdgcn_exp2f(s)) & m);
}

// hi/lo split: x ~= hi + lo, both bf16 RNE
__device__ inline void split8(const float* x, short8& hi, short8& lo) {
  #pragma unroll
  for (int i = 0; i < 8; ++i) {
    const uint16_t h = f2bf(x[i]);
    hi[i] = (short)h;
    lo[i] = (short)f2bf(x[i] - __uint_as_float((uint32_t)h << 16));
  }
}
__device__ inline short8 round8(const float* x) {
  short8 r;
  #pragma unroll
  for (int i = 0; i < 8; ++i) r[i] = (short)f2bf(x[i]);
  return r;
}

// ---------------- Kernel 1: MFMA QKV projection (hi/lo split) + bitpack ----------------
// (unchanged from round 10 — validated, ~29 us)
__global__ __launch_bounds__(512) void qkv_kernel(
    const float* __restrict__ hin,
    const float* __restrict__ Wq, const float* __restrict__ Wk, const float* __restrict__ Wv,
    const int* __restrict__ adj,
    uint16_t* __restrict__ Qf, uint16_t* __restrict__ Kf, uint16_t* __restrict__ Vf,
    uint32_t* __restrict__ bits)
{
  const int t = threadIdx.x;
  const int hd = t >> 6;            // wave = head
  const int l = t & 63;
  const int g = l >> 4, c = l & 15;

  // ---- adjacency bit-pack (r3-validated inner code; 8 waves/block, 4 rows/wave) ----
  {
    const int gw = blockIdx.x * 8 + hd;              // 4096 waves
    const int* asrc = adj + (size_t)gw * 4096 + l;   // 64 chunks x 64 ints
    uint2* bdst = reinterpret_cast<uint2*>(bits) + (size_t)gw * 64;
    #pragma unroll 4
    for (int cc = 0; cc < 64; ++cc) {
      const unsigned long long m = __ballot(asrc[(size_t)cc * 64] != 0);
      if (l == 0) bdst[cc] = make_uint2((uint32_t)m, (uint32_t)(m >> 32));
    }
  }

  const int tokenblk = blockIdx.x;  // 32 tokens per block
  const int b = tokenblk >> 5;
  const int kblk = tokenblk & 31;

  f32x4 Qa0 = {0,0,0,0}, Qa1 = {0,0,0,0};
  f32x4 Ka0 = {0,0,0,0}, Ka1 = {0,0,0,0};
  f32x4 Va0 = {0,0,0,0}, Va1 = {0,0,0,0};

  #pragma unroll
  for (int s = 0; s < 4; ++s) {
    const int ebase = (s * 32 + 4 * g) * 16 + c;
    const float* wqp = Wq + hd * 2048 + ebase;
    const float* wkp = Wk + hd * 2048 + ebase;
    const float* wvp = Wv + hd * 2048 + ebase;
    float wx[8];
    short8 wqh, wql, wkh, wkl, wv8;
    wx[0]=wqp[0]; wx[1]=wqp[16]; wx[2]=wqp[32]; wx[3]=wqp[48];
    wx[4]=wqp[256]; wx[5]=wqp[272]; wx[6]=wqp[288]; wx[7]=wqp[304];
    split8(wx, wqh, wql);
    wx[0]=wkp[0]; wx[1]=wkp[16]; wx[2]=wkp[32]; wx[3]=wkp[48];
    wx[4]=wkp[256]; wx[5]=wkp[272]; wx[6]=wkp[288]; wx[7]=wkp[304];
    split8(wx, wkh, wkl);
    wx[0]=wvp[0]; wx[1]=wvp[16]; wx[2]=wvp[32]; wx[3]=wvp[48];
    wx[4]=wvp[256]; wx[5]=wvp[272]; wx[6]=wvp[288]; wx[7]=wvp[304];
    wv8 = round8(wx);

    #pragma unroll
    for (int tile = 0; tile < 2; ++tile) {
      const size_t grow = (size_t)tokenblk * 32 + tile * 16 + c;
      const float4 lo4 = *reinterpret_cast<const float4*>(hin + grow * 128 + s * 32 + 4 * g);
      const float4 hi4 = *reinterpret_cast<const float4*>(hin + grow * 128 + s * 32 + 16 + 4 * g);
      float hx[8];
      hx[0]=lo4.x; hx[1]=lo4.y; hx[2]=lo4.z; hx[3]=lo4.w;
      hx[4]=hi4.x; hx[5]=hi4.y; hx[6]=hi4.z; hx[7]=hi4.w;
      short8 hh, hl; split8(hx, hh, hl);

      if (tile == 0) {
        Qa0 = __builtin_amdgcn_mfma_f32_16x16x32_bf16(wqh, hh, Qa0, 0, 0, 0);
        Qa0 = __builtin_amdgcn_mfma_f32_16x16x32_bf16(wqh, hl, Qa0, 0, 0, 0);
        Qa0 = __builtin_amdgcn_mfma_f32_16x16x32_bf16(wql, hh, Qa0, 0, 0, 0);
        Ka0 = __builtin_amdgcn_mfma_f32_16x16x32_bf16(wkh, hh, Ka0, 0, 0, 0);
        Ka0 = __builtin_amdgcn_mfma_f32_16x16x32_bf16(wkh, hl, Ka0, 0, 0, 0);
        Ka0 = __builtin_amdgcn_mfma_f32_16x16x32_bf16(wkl, hh, Ka0, 0, 0, 0);
        Va0 = __builtin_amdgcn_mfma_f32_16x16x32_bf16(hh, wv8, Va0, 0, 0, 0);
        Va0 = __builtin_amdgcn_mfma_f32_16x16x32_bf16(hl, wv8, Va0, 0, 0, 0);
      } else {
        Qa1 = __builtin_amdgcn_mfma_f32_16x16x32_bf16(wqh, hh, Qa1, 0, 0, 0);
        Qa1 = __builtin_amdgcn_mfma_f32_16x16x32_bf16(wqh, hl, Qa1, 0, 0, 0);
        Qa1 = __builtin_amdgcn_mfma_f32_16x16x32_bf16(wql, hh, Qa1, 0, 0, 0);
        Ka1 = __builtin_amdgcn_mfma_f32_16x16x32_bf16(wkh, hh, Ka1, 0, 0, 0);
        Ka1 = __builtin_amdgcn_mfma_f32_16x16x32_bf16(wkh, hl, Ka1, 0, 0, 0);
        Ka1 = __builtin_amdgcn_mfma_f32_16x16x32_bf16(wkl, hh, Ka1, 0, 0, 0);
        Va1 = __builtin_amdgcn_mfma_f32_16x16x32_bf16(hh, wv8, Va1, 0, 0, 0);
        Va1 = __builtin_amdgcn_mfma_f32_16x16x32_bf16(hl, wv8, Va1, 0, 0, 0);
      }
    }
  }

  const int qt0 = kblk * 2;
  {
    uint2 q0, q1;
    q0.x = pk2(Qa0[0] * SCALE, Qa0[1] * SCALE);
    q0.y = pk2(Qa0[2] * SCALE, Qa0[3] * SCALE);
    q1.x = pk2(Qa1[0] * SCALE, Qa1[1] * SCALE);
    q1.y = pk2(Qa1[2] * SCALE, Qa1[3] * SCALE);
    uint16_t* qp = Qf + ((((size_t)b * Hc + hd) * 64 + qt0) * 64 + l) * 4;
    *reinterpret_cast<uint2*>(qp) = q0;
    *reinterpret_cast<uint2*>(qp + 256) = q1;
  }
  {
    int4v kw;
    kw[0] = (int)pk2(Ka0[0], Ka0[1]); kw[1] = (int)pk2(Ka0[2], Ka0[3]);
    kw[2] = (int)pk2(Ka1[0], Ka1[1]); kw[3] = (int)pk2(Ka1[2], Ka1[3]);
    *reinterpret_cast<int4v*>(Kf + ((((size_t)b * Hc + hd) * 32 + kblk) * 64 + l) * 8) = kw;
    int4v vw;
    vw[0] = (int)pk2(Va0[0], Va0[1]); vw[1] = (int)pk2(Va0[2], Va0[3]);
    vw[2] = (int)pk2(Va1[0], Va1[1]); vw[3] = (int)pk2(Va1[2], Va1[3]);
    *reinterpret_cast<int4v*>(Vf + ((((size_t)b * Hc + hd) * 32 + kblk) * 64 + l) * 8) = vw;
  }
}

// ---------------- Kernel 2: 16x16-fragment MFMA masked attention + out-proj ----------
// r8 math, with: __launch_bounds__(512,4) -> 128-reg budget (r10's (512,8) compile
// starved VGPRs to 24 and serialized every K/V load), explicit register
// double-buffer prefetch, int-level operand construction.
__global__ __launch_bounds__(512, 4) void attn_kernel(
    const uint16_t* __restrict__ Qf, const uint16_t* __restrict__ Kf,
    const uint16_t* __restrict__ Vf, const uint32_t* __restrict__ bits,
    const float* __restrict__ hin, const float* __restrict__ Wout,
    float* __restrict__ out)
{
  __shared__ uint32_t adj_lds[16][33];   // [q-row][word], padded
  __shared__ float heads[16][132];       // [q-row][h*16+kd], padded
  __shared__ float S_lds[8][16];         // [head][q-row]

  const int t = threadIdx.x;
  // XCD-aware swizzle: 1024 blocks, 128/XCD
  const int bid = blockIdx.x;
  const int swz = (bid & 7) * 128 + (bid >> 3);
  const int b = swz >> 6;
  const int qblk = swz & 63;
  const int hd = t >> 6, l = t & 63;
  const int g = l >> 4, q = l & 15;

  // stage adjacency bit words: 16 rows x 32 words, fully coalesced
  adj_lds[t >> 5][t & 31] =
      bits[((size_t)b * Nc + qblk * 16 + (t >> 5)) * 32 + (t & 31)];

  // Q fragment: 4 bf16 (kd = 4g+i), upper 4 k-slots zero
  const short4v q4 = *reinterpret_cast<const short4v*>(
      Qf + ((((size_t)b * Hc + hd) * 64 + qblk) * 64 + l) * 4);
  short8 qf8;
  #pragma unroll
  for (int i = 0; i < 4; ++i) { qf8[i] = q4[i]; qf8[4 + i] = 0; }

  __syncthreads();

  f32x4 acc = {0.f, 0.f, 0.f, 0.f};
  const f32x4 zc = {0.f, 0.f, 0.f, 0.f};
  float S = 0.f;

  const uint16_t* kb = Kf + (((size_t)b * Hc + hd) * 32) * 512 + (size_t)l * 8;
  const uint16_t* vb = Vf + (((size_t)b * Hc + hd) * 32) * 512 + (size_t)l * 8;

  // prologue: loads for kblk = 0
  int4v kfw = *reinterpret_cast<const int4v*>(kb);
  int4v vfw = *reinterpret_cast<const int4v*>(vb);

  #pragma unroll 2
  for (int kblk = 0; kblk < 32; ++kblk) {
    const int4v kc = kfw, vc = vfw;
    // prefetch next iteration (unconditional; one-past-end lands in adjacent
    // workspace region — mapped, never consumed)
    kfw = *reinterpret_cast<const int4v*>(kb + (size_t)(kblk + 1) * 512);
    vfw = *reinterpret_cast<const int4v*>(vb + (size_t)(kblk + 1) * 512);

    int4v a1w, a2w;
    a1w[0] = kc[0]; a1w[1] = kc[1]; a1w[2] = 0; a1w[3] = 0;
    a2w[0] = kc[2]; a2w[1] = kc[3]; a2w[2] = 0; a2w[3] = 0;
    short8 a1, a2, vf;
    __builtin_memcpy(&a1, &a1w, 16);
    __builtin_memcpy(&a2, &a2w, 16);
    __builtin_memcpy(&vf, &vc, 16);

    const f32x4 s0 = __builtin_amdgcn_mfma_f32_16x16x32_bf16(a1, qf8, zc, 0, 0, 0);
    const f32x4 s1 = __builtin_amdgcn_mfma_f32_16x16x32_bf16(a2, qf8, zc, 0, 0, 0);

    const uint32_t wsh = adj_lds[q][kblk] >> (4 * g);   // keys 4g+i -> bits i / 16+i

    const float p0 = mexp(s0[0], wsh, 0),  p1 = mexp(s0[1], wsh, 1);
    const float p2 = mexp(s0[2], wsh, 2),  p3 = mexp(s0[3], wsh, 3);
    const float p4 = mexp(s1[0], wsh, 16), p5 = mexp(s1[1], wsh, 17);
    const float p6 = mexp(s1[2], wsh, 18), p7 = mexp(s1[3], wsh, 19);
    S += ((p0 + p1) + (p2 + p3)) + ((p4 + p5) + (p6 + p7));

    int4v paw;
    paw[0] = (int)cvt_pk_bf16(p0, p1);
    paw[1] = (int)cvt_pk_bf16(p2, p3);
    paw[2] = (int)cvt_pk_bf16(p4, p5);
    paw[3] = (int)cvt_pk_bf16(p6, p7);
    short8 pa; __builtin_memcpy(&pa, &paw, 16);

    acc = __builtin_amdgcn_mfma_f32_16x16x32_bf16(pa, vf, acc, 0, 0, 0);
  }

  // ---- S reduce over the 4 lane-groups holding the same q ----
  S += __shfl_xor(S, 16);
  S += __shfl_xor(S, 32);

  // acc[i] = out[q=4g+i][kd=l&15] (unnormalized); park in LDS
  #pragma unroll
  for (int i = 0; i < 4; ++i) heads[4 * g + i][hd * 16 + q] = acc[i];
  if (l < 16) S_lds[hd][l] = S;
  __syncthreads();
  if (t < 128) S_lds[t >> 4][t & 15] = 1.0f / S_lds[t >> 4][t & 15];
  __syncthreads();
  #pragma unroll
  for (int i = 0; i < 4; ++i) {
    const int idx = t + i * 512;
    const int rr = idx >> 7, cc = idx & 127;
    heads[rr][cc] *= S_lds[cc >> 4][rr];
  }
  __syncthreads();

  // ---- output projection + residual: thread = (q2 = t>>5, eg = t&31 -> 4 e-cols) ----
  const int q2 = t >> 5, eg = t & 31;
  const size_t orow = (size_t)b * Nc + qblk * 16 + q2;
  float4 o = *(reinterpret_cast<const float4*>(hin + orow * Ec) + eg);
  #pragma unroll 4
  for (int hk = 0; hk < HKc; ++hk) {
    const float hv = heads[q2][hk];                       // 32-lane broadcast
    const float4 wv4 = *(reinterpret_cast<const float4*>(Wout + (size_t)hk * Ec) + eg);
    o.x = fmaf(hv, wv4.x, o.x); o.y = fmaf(hv, wv4.y, o.y);
    o.z = fmaf(hv, wv4.z, o.z); o.w = fmaf(hv, wv4.w, o.w);
  }
  *(reinterpret_cast<float4*>(out + orow * Ec) + eg) = o;
}

} // namespace

extern "C" void kernel_launch(void* const* d_in, const int* in_sizes, int n_in,
                              void* d_out, int out_size, void* d_ws, size_t ws_size,
                              hipStream_t stream) {
  (void)in_sizes; (void)n_in; (void)out_size; (void)ws_size;
  const float* h   = (const float*)d_in[0];
  const int*   adj = (const int*)d_in[1];
  const float* Wq  = (const float*)d_in[2];
  const float* Wk  = (const float*)d_in[3];
  const float* Wv  = (const float*)d_in[4];
  const float* Wo  = (const float*)d_in[5];
  float* out = (float*)d_out;

  // workspace: Qf/Kf/Vf bf16 fragment buffers (4 MB each) + adjacency bits (2 MB)
  uint16_t* Qf = (uint16_t*)d_ws;
  uint16_t* Kf = Qf + (size_t)Bc * Hc * Nc * KDc;
  uint16_t* Vf = Kf + (size_t)Bc * Hc * Nc * KDc;
  uint32_t* bits = (uint32_t*)(Vf + (size_t)Bc * Hc * Nc * KDc);

  qkv_kernel<<<Bc * Nc / 32, 512, 0, stream>>>(h, Wq, Wk, Wv, adj, Qf, Kf, Vf, bits);
  attn_kernel<<<Bc * (Nc / 16), 512, 0, stream>>>(Qf, Kf, Vf, bits, h, Wo, out);
}

// Round 12
// 72.523 us; speedup vs baseline: 1.8922x; 1.1951x over previous
//
#include <hip/hip_runtime.h>
#include <hip/hip_bf16.h>
#include <math.h>
#include <stdint.h>

namespace {

constexpr int Bc = 16, Nc = 1024, Ec = 128, Hc = 8, KDc = 16, HKc = 128;
// 1/sqrt(KD) * log2(e): fold softmax scale + base-2 conversion into Q
constexpr float SCALE = 0.25f * 1.4426950408889634f;

typedef __attribute__((ext_vector_type(4))) short short4v;
typedef __attribute__((ext_vector_type(8))) short short8;
typedef __attribute__((ext_vector_type(4))) float f32x4;
typedef __attribute__((ext_vector_type(4))) int int4v;

__device__ inline uint16_t f2bf(float f) {
  __hip_bfloat16 h = __float2bfloat16(f);
  uint16_t s; __builtin_memcpy(&s, &h, 2);
  return s;
}

// RNE pair pack for output stores
__device__ inline uint32_t pk2(float a, float b) {
  return (uint32_t)f2bf(a) | ((uint32_t)f2bf(b) << 16);
}

// packed f32->bf16 (P-values / epilogue fragments)
__device__ inline uint32_t cvt_pk_bf16(float a, float b) {
  uint32_t r;
  asm("v_cvt_pk_bf16_f32 %0, %1, %2" : "=v"(r) : "v"(a), "v"(b));
  return r;
}

// masked exp2: p = exp2(s) if adjacency bit set else 0  (sbfe -> 0/-1 mask)
__device__ inline float mexp(float s, uint32_t w, int bit) {
  const uint32_t m = (uint32_t)__builtin_amdgcn_sbfe((int)w, bit, 1);
  return __uint_as_float(__float_as_uint(__builtin_amdgcn_exp2f(s)) & m);
}

// hi/lo split: x ~= hi + lo, both bf16 RNE
__device__ inline void split8(const float* x, short8& hi, short8& lo) {
  #pragma unroll
  for (int i = 0; i < 8; ++i) {
    const uint16_t h = f2bf(x[i]);
    hi[i] = (short)h;
    lo[i] = (short)f2bf(x[i] - __uint_as_float((uint32_t)h << 16));
  }
}
__device__ inline short8 round8(const float* x) {
  short8 r;
  #pragma unroll
  for (int i = 0; i < 8; ++i) r[i] = (short)f2bf(x[i]);
  return r;
}

// ---------------- Kernel 1: MFMA QKV projection (hi/lo) + bitpack + WoutF pack ----
// (r10/r11-validated; block 0 additionally packs Wout into bf16 fragment layout:
//  WoutF[((etile*4 + kstep)*64 + lane)*8 + elem] = Wout[hk][e], with
//  hk = (elem&3) + 4*(lane>>4) + 16*(elem>>2) + 32*kstep, e = etile*16 + (lane&15))
__global__ __launch_bounds__(512) void qkv_kernel(
    const float* __restrict__ hin,
    const float* __restrict__ Wq, const float* __restrict__ Wk, const float* __restrict__ Wv,
    const float* __restrict__ Wout, const int* __restrict__ adj,
    uint16_t* __restrict__ Qf, uint16_t* __restrict__ Kf, uint16_t* __restrict__ Vf,
    uint32_t* __restrict__ bits, uint16_t* __restrict__ WoutF)
{
  const int t = threadIdx.x;
  const int hd = t >> 6;            // wave = head
  const int l = t & 63;
  const int g = l >> 4, c = l & 15;

  // ---- adjacency bit-pack ----
  {
    const int gw = blockIdx.x * 8 + hd;              // 4096 waves
    const int* asrc = adj + (size_t)gw * 4096 + l;   // 64 chunks x 64 ints
    uint2* bdst = reinterpret_cast<uint2*>(bits) + (size_t)gw * 64;
    #pragma unroll 4
    for (int cc = 0; cc < 64; ++cc) {
      const unsigned long long m = __ballot(asrc[(size_t)cc * 64] != 0);
      if (l == 0) bdst[cc] = make_uint2((uint32_t)m, (uint32_t)(m >> 32));
    }
  }

  // ---- Wout fragment pack (block 0 only; 16384 elems, 32/thread) ----
  if (blockIdx.x == 0) {
    #pragma unroll 4
    for (int it = 0; it < 32; ++it) {
      const int idx = t + it * 512;
      const int elem = idx & 7, lane = (idx >> 3) & 63;
      const int kstep = (idx >> 9) & 3, etile = idx >> 11;
      const int hk = (elem & 3) + 4 * (lane >> 4) + 16 * (elem >> 2) + 32 * kstep;
      const int e = etile * 16 + (lane & 15);
      WoutF[idx] = f2bf(Wout[hk * 128 + e]);
    }
  }

  const int tokenblk = blockIdx.x;  // 32 tokens per block
  const int b = tokenblk >> 5;
  const int kblk = tokenblk & 31;

  f32x4 Qa0 = {0,0,0,0}, Qa1 = {0,0,0,0};
  f32x4 Ka0 = {0,0,0,0}, Ka1 = {0,0,0,0};
  f32x4 Va0 = {0,0,0,0}, Va1 = {0,0,0,0};

  #pragma unroll
  for (int s = 0; s < 4; ++s) {
    const int ebase = (s * 32 + 4 * g) * 16 + c;
    const float* wqp = Wq + hd * 2048 + ebase;
    const float* wkp = Wk + hd * 2048 + ebase;
    const float* wvp = Wv + hd * 2048 + ebase;
    float wx[8];
    short8 wqh, wql, wkh, wkl, wv8;
    wx[0]=wqp[0]; wx[1]=wqp[16]; wx[2]=wqp[32]; wx[3]=wqp[48];
    wx[4]=wqp[256]; wx[5]=wqp[272]; wx[6]=wqp[288]; wx[7]=wqp[304];
    split8(wx, wqh, wql);
    wx[0]=wkp[0]; wx[1]=wkp[16]; wx[2]=wkp[32]; wx[3]=wkp[48];
    wx[4]=wkp[256]; wx[5]=wkp[272]; wx[6]=wkp[288]; wx[7]=wkp[304];
    split8(wx, wkh, wkl);
    wx[0]=wvp[0]; wx[1]=wvp[16]; wx[2]=wvp[32]; wx[3]=wvp[48];
    wx[4]=wvp[256]; wx[5]=wvp[272]; wx[6]=wvp[288]; wx[7]=wvp[304];
    wv8 = round8(wx);

    #pragma unroll
    for (int tile = 0; tile < 2; ++tile) {
      const size_t grow = (size_t)tokenblk * 32 + tile * 16 + c;
      const float4 lo4 = *reinterpret_cast<const float4*>(hin + grow * 128 + s * 32 + 4 * g);
      const float4 hi4 = *reinterpret_cast<const float4*>(hin + grow * 128 + s * 32 + 16 + 4 * g);
      float hx[8];
      hx[0]=lo4.x; hx[1]=lo4.y; hx[2]=lo4.z; hx[3]=lo4.w;
      hx[4]=hi4.x; hx[5]=hi4.y; hx[6]=hi4.z; hx[7]=hi4.w;
      short8 hh, hl; split8(hx, hh, hl);

      if (tile == 0) {
        Qa0 = __builtin_amdgcn_mfma_f32_16x16x32_bf16(wqh, hh, Qa0, 0, 0, 0);
        Qa0 = __builtin_amdgcn_mfma_f32_16x16x32_bf16(wqh, hl, Qa0, 0, 0, 0);
        Qa0 = __builtin_amdgcn_mfma_f32_16x16x32_bf16(wql, hh, Qa0, 0, 0, 0);
        Ka0 = __builtin_amdgcn_mfma_f32_16x16x32_bf16(wkh, hh, Ka0, 0, 0, 0);
        Ka0 = __builtin_amdgcn_mfma_f32_16x16x32_bf16(wkh, hl, Ka0, 0, 0, 0);
        Ka0 = __builtin_amdgcn_mfma_f32_16x16x32_bf16(wkl, hh, Ka0, 0, 0, 0);
        Va0 = __builtin_amdgcn_mfma_f32_16x16x32_bf16(hh, wv8, Va0, 0, 0, 0);
        Va0 = __builtin_amdgcn_mfma_f32_16x16x32_bf16(hl, wv8, Va0, 0, 0, 0);
      } else {
        Qa1 = __builtin_amdgcn_mfma_f32_16x16x32_bf16(wqh, hh, Qa1, 0, 0, 0);
        Qa1 = __builtin_amdgcn_mfma_f32_16x16x32_bf16(wqh, hl, Qa1, 0, 0, 0);
        Qa1 = __builtin_amdgcn_mfma_f32_16x16x32_bf16(wql, hh, Qa1, 0, 0, 0);
        Ka1 = __builtin_amdgcn_mfma_f32_16x16x32_bf16(wkh, hh, Ka1, 0, 0, 0);
        Ka1 = __builtin_amdgcn_mfma_f32_16x16x32_bf16(wkh, hl, Ka1, 0, 0, 0);
        Ka1 = __builtin_amdgcn_mfma_f32_16x16x32_bf16(wkl, hh, Ka1, 0, 0, 0);
        Va1 = __builtin_amdgcn_mfma_f32_16x16x32_bf16(hh, wv8, Va1, 0, 0, 0);
        Va1 = __builtin_amdgcn_mfma_f32_16x16x32_bf16(hl, wv8, Va1, 0, 0, 0);
      }
    }
  }

  const int qt0 = kblk * 2;
  {
    uint2 q0, q1;
    q0.x = pk2(Qa0[0] * SCALE, Qa0[1] * SCALE);
    q0.y = pk2(Qa0[2] * SCALE, Qa0[3] * SCALE);
    q1.x = pk2(Qa1[0] * SCALE, Qa1[1] * SCALE);
    q1.y = pk2(Qa1[2] * SCALE, Qa1[3] * SCALE);
    uint16_t* qp = Qf + ((((size_t)b * Hc + hd) * 64 + qt0) * 64 + l) * 4;
    *reinterpret_cast<uint2*>(qp) = q0;
    *reinterpret_cast<uint2*>(qp + 256) = q1;
  }
  {
    int4v kw;
    kw[0] = (int)pk2(Ka0[0], Ka0[1]); kw[1] = (int)pk2(Ka0[2], Ka0[3]);
    kw[2] = (int)pk2(Ka1[0], Ka1[1]); kw[3] = (int)pk2(Ka1[2], Ka1[3]);
    *reinterpret_cast<int4v*>(Kf + ((((size_t)b * Hc + hd) * 32 + kblk) * 64 + l) * 8) = kw;
    int4v vw;
    vw[0] = (int)pk2(Va0[0], Va0[1]); vw[1] = (int)pk2(Va0[2], Va0[3]);
    vw[2] = (int)pk2(Va1[0], Va1[1]); vw[3] = (int)pk2(Va1[2], Va1[3]);
    *reinterpret_cast<int4v*>(Vf + ((((size_t)b * Hc + hd) * 32 + kblk) * 64 + l) * 8) = vw;
  }
}

// ---------------- Kernel 2: 16x16-fragment MFMA masked attention + MFMA out-proj ----
// Main loop = r11 (validated math). Epilogue rewritten as MFMA: wave hd = e-tile,
// A = normalized heads from LDS (same k-map as B), B = prepacked WoutF fragments.
__global__ __launch_bounds__(512, 4) void attn_kernel(
    const uint16_t* __restrict__ Qf, const uint16_t* __restrict__ Kf,
    const uint16_t* __restrict__ Vf, const uint32_t* __restrict__ bits,
    const uint16_t* __restrict__ WoutF,
    const float* __restrict__ hin, float* __restrict__ out)
{
  __shared__ uint32_t adj_lds[16][33];   // [q-row][word], padded
  __shared__ float heads[16][132];       // [q-row][h*16+kd], padded
  __shared__ float S_lds[8][16];         // [head][q-row]

  const int t = threadIdx.x;
  // XCD-aware swizzle: 1024 blocks, 128/XCD
  const int bid = blockIdx.x;
  const int swz = (bid & 7) * 128 + (bid >> 3);
  const int b = swz >> 6;
  const int qblk = swz & 63;
  const int hd = t >> 6, l = t & 63;
  const int g = l >> 4, q = l & 15;

  // stage adjacency bit words: 16 rows x 32 words, fully coalesced
  adj_lds[t >> 5][t & 31] =
      bits[((size_t)b * Nc + qblk * 16 + (t >> 5)) * 32 + (t & 31)];

  // Q fragment: 4 bf16 (kd = 4g+i), upper 4 k-slots zero
  const short4v q4 = *reinterpret_cast<const short4v*>(
      Qf + ((((size_t)b * Hc + hd) * 64 + qblk) * 64 + l) * 4);
  short8 qf8;
  #pragma unroll
  for (int i = 0; i < 4; ++i) { qf8[i] = q4[i]; qf8[4 + i] = 0; }

  __syncthreads();

  f32x4 acc = {0.f, 0.f, 0.f, 0.f};
  const f32x4 zc = {0.f, 0.f, 0.f, 0.f};
  float S = 0.f;

  const uint16_t* kb = Kf + (((size_t)b * Hc + hd) * 32) * 512 + (size_t)l * 8;
  const uint16_t* vb = Vf + (((size_t)b * Hc + hd) * 32) * 512 + (size_t)l * 8;

  // prologue: loads for kblk = 0
  int4v kfw = *reinterpret_cast<const int4v*>(kb);
  int4v vfw = *reinterpret_cast<const int4v*>(vb);

  #pragma unroll 2
  for (int kblk = 0; kblk < 32; ++kblk) {
    const int4v kc = kfw, vc = vfw;
    // prefetch next iteration (one-past-end lands in adjacent mapped workspace)
    kfw = *reinterpret_cast<const int4v*>(kb + (size_t)(kblk + 1) * 512);
    vfw = *reinterpret_cast<const int4v*>(vb + (size_t)(kblk + 1) * 512);

    int4v a1w, a2w;
    a1w[0] = kc[0]; a1w[1] = kc[1]; a1w[2] = 0; a1w[3] = 0;
    a2w[0] = kc[2]; a2w[1] = kc[3]; a2w[2] = 0; a2w[3] = 0;
    short8 a1, a2, vf;
    __builtin_memcpy(&a1, &a1w, 16);
    __builtin_memcpy(&a2, &a2w, 16);
    __builtin_memcpy(&vf, &vc, 16);

    const f32x4 s0 = __builtin_amdgcn_mfma_f32_16x16x32_bf16(a1, qf8, zc, 0, 0, 0);
    const f32x4 s1 = __builtin_amdgcn_mfma_f32_16x16x32_bf16(a2, qf8, zc, 0, 0, 0);

    const uint32_t wsh = adj_lds[q][kblk] >> (4 * g);   // keys 4g+i -> bits i / 16+i

    const float p0 = mexp(s0[0], wsh, 0),  p1 = mexp(s0[1], wsh, 1);
    const float p2 = mexp(s0[2], wsh, 2),  p3 = mexp(s0[3], wsh, 3);
    const float p4 = mexp(s1[0], wsh, 16), p5 = mexp(s1[1], wsh, 17);
    const float p6 = mexp(s1[2], wsh, 18), p7 = mexp(s1[3], wsh, 19);
    S += ((p0 + p1) + (p2 + p3)) + ((p4 + p5) + (p6 + p7));

    int4v paw;
    paw[0] = (int)cvt_pk_bf16(p0, p1);
    paw[1] = (int)cvt_pk_bf16(p2, p3);
    paw[2] = (int)cvt_pk_bf16(p4, p5);
    paw[3] = (int)cvt_pk_bf16(p6, p7);
    short8 pa; __builtin_memcpy(&pa, &paw, 16);

    acc = __builtin_amdgcn_mfma_f32_16x16x32_bf16(pa, vf, acc, 0, 0, 0);
  }

  // ---- S reduce over the 4 lane-groups holding the same q ----
  S += __shfl_xor(S, 16);
  S += __shfl_xor(S, 32);

  // acc[i] = out[q=4g+i][kd=l&15] (unnormalized); park in LDS
  #pragma unroll
  for (int i = 0; i < 4; ++i) heads[4 * g + i][hd * 16 + q] = acc[i];
  if (l < 16) S_lds[hd][l] = S;
  __syncthreads();
  if (t < 128) S_lds[t >> 4][t & 15] = 1.0f / S_lds[t >> 4][t & 15];
  __syncthreads();
  #pragma unroll
  for (int i = 0; i < 4; ++i) {
    const int idx = t + i * 512;
    const int rr = idx >> 7, cc = idx & 127;
    heads[rr][cc] *= S_lds[cc >> 4][rr];
  }
  __syncthreads();

  // ---- MFMA output projection + residual: wave hd = e-tile, 4 k-steps of 32 ----
  // A lane l elem e: heads[q=l&15][hk = (e&3)+4g+16*(e>>2)+32*k]  (same k-map as WoutF)
  f32x4 od = {0.f, 0.f, 0.f, 0.f};
  const uint16_t* wfp = WoutF + ((size_t)hd * 4) * 512 + (size_t)l * 8;
  #pragma unroll
  for (int k = 0; k < 4; ++k) {
    const float* hr = &heads[q][32 * k + 4 * g];
    int4v aw;
    aw[0] = (int)cvt_pk_bf16(hr[0],  hr[1]);
    aw[1] = (int)cvt_pk_bf16(hr[2],  hr[3]);
    aw[2] = (int)cvt_pk_bf16(hr[16], hr[17]);
    aw[3] = (int)cvt_pk_bf16(hr[18], hr[19]);
    short8 af; __builtin_memcpy(&af, &aw, 16);
    const short8 bf = *reinterpret_cast<const short8*>(wfp + (size_t)k * 512);
    od = __builtin_amdgcn_mfma_f32_16x16x32_bf16(af, bf, od, 0, 0, 0);
  }
  // D: row = 4g+i = q-row, col = l&15 = e within tile hd
  const size_t orow0 = (size_t)b * Nc + qblk * 16;
  const int ecol = hd * 16 + q;
  #pragma unroll
  for (int i = 0; i < 4; ++i) {
    const size_t off = (orow0 + 4 * g + i) * Ec + ecol;
    out[off] = od[i] + hin[off];
  }
}

} // namespace

extern "C" void kernel_launch(void* const* d_in, const int* in_sizes, int n_in,
                              void* d_out, int out_size, void* d_ws, size_t ws_size,
                              hipStream_t stream) {
  (void)in_sizes; (void)n_in; (void)out_size; (void)ws_size;
  const float* h   = (const float*)d_in[0];
  const int*   adj = (const int*)d_in[1];
  const float* Wq  = (const float*)d_in[2];
  const float* Wk  = (const float*)d_in[3];
  const float* Wv  = (const float*)d_in[4];
  const float* Wo  = (const float*)d_in[5];
  float* out = (float*)d_out;

  // workspace: Qf/Kf/Vf (4 MB each) + bits (2 MB) + WoutF (32 KB)
  uint16_t* Qf = (uint16_t*)d_ws;
  uint16_t* Kf = Qf + (size_t)Bc * Hc * Nc * KDc;
  uint16_t* Vf = Kf + (size_t)Bc * Hc * Nc * KDc;
  uint32_t* bits = (uint32_t*)(Vf + (size_t)Bc * Hc * Nc * KDc);
  uint16_t* WoutF = (uint16_t*)(bits + (size_t)Bc * Nc * 32);

  qkv_kernel<<<Bc * Nc / 32, 512, 0, stream>>>(h, Wq, Wk, Wv, Wo, adj,
                                               Qf, Kf, Vf, bits, WoutF);
  attn_kernel<<<Bc * (Nc / 16), 512, 0, stream>>>(Qf, Kf, Vf, bits, WoutF, h, out);
}